// Round 6
// baseline (543.293 us; speedup 1.0000x reference)
//
#include <hip/hip_runtime.h>
#include <hip/hip_bf16.h>
#include <math.h>

#define BB 16
#define NN_ 1024
#define TT 12

typedef __attribute__((ext_vector_type(8))) short bf16x8;
typedef __attribute__((ext_vector_type(4))) float f32x4;

// ---------------- workspace layout (float units) ----------------
static const size_t ACC_OFF    = 0;          // 16
static const size_t COLSUM_OFF = 16;         // B*N = 16384
static const size_t TAT_OFF    = 16400;      // B*T*T = 2304
static const size_t LHST_OFF   = 18704;      // B*N*T = 196608
static const size_t RHS2_OFF   = 215312;     // B*T*N = 196608
static const size_t VSB_OFF    = 411920;     // N*N bf16 = 524288 floats
static const size_t SIG2B_OFF  = 936208;     // B*N*N bf16 = 8388608 floats
static const size_t CHEBB_OFF  = 9324816;    // 3*N*N bf16 = 1572864 floats
static const size_t EXPS_OFF   = 10897680;   // B*N*N bf16 = 8388608 floats
static const size_t RHSC0_OFF  = 19286288;   // B*K*N*F*T fp32 = 1769472
static const size_t RHSC1_OFF  = 21055760;   // B*K*N*F*T fp32 = 1769472
static const size_t WTG_OFF    = 22825232;   // 192*64 bf16 = 6144 floats
// total 22831376 floats = ~91 MB

__device__ __forceinline__ float wave_reduce_sum(float v) {
    #pragma unroll
    for (int off = 32; off > 0; off >>= 1) v += __shfl_down(v, off);
    return v;
}

__device__ __forceinline__ unsigned short f2b(float f) {
    __hip_bfloat16 h = __float2bfloat16(f);
    return *(unsigned short*)&h;
}
__device__ __forceinline__ float b2f(unsigned short u) {
    return __uint_as_float(((unsigned int)u) << 16);
}

// ---------------- init: zero acc + colsum ----------------
__global__ void k_init(float* __restrict__ ws) {
    int i = blockIdx.x * 256 + threadIdx.x;
    if (i < 16400) ws[i] = 0.f;
}

// ---------------- tcw -> WtG[d*64+c][cp] bf16 (one block) ----------------
__global__ __launch_bounds__(256) void k_cvtw(
    const float* __restrict__ tcw, unsigned short* __restrict__ WtG)
{
    for (int j = threadIdx.x; j < 12288; j += 256) {
        const int row = j >> 6;            // d*64 + c
        const int cp  = j & 63;
        const int d   = row >> 6;
        const int c   = row & 63;
        WtG[j] = f2b(tcw[c * 192 + 3 * cp + d]);
    }
}

// ---------------- temporal attention -> tat (B,T,T), 256 threads ----------------
__global__ __launch_bounds__(256) void k_temporal(
    const float* __restrict__ x, const float* __restrict__ U1,
    const float* __restrict__ U2, const float* __restrict__ U3,
    const float* __restrict__ be, const float* __restrict__ Ve,
    float* __restrict__ tat)
{
    const int b = blockIdx.x;
    const int tid = threadIdx.x;
    const int wid = tid >> 6, lane = tid & 63;
    float lA[36], lM[36];
    #pragma unroll
    for (int i = 0; i < 36; ++i) { lA[i] = 0.f; lM[i] = 0.f; }
    const float u30 = U3[0], u31 = U3[1], u32 = U3[2];
    for (int n = tid; n < NN_; n += 256) {
        const float* xp = x + ((size_t)b * NN_ + n) * 36;
        float xr[36];
        #pragma unroll
        for (int i = 0; i < 9; ++i) *(float4*)&xr[i*4] = *(const float4*)(xp + i*4);
        const float u1  = U1[n];
        const float u20 = U2[n], u21 = U2[NN_ + n], u22 = U2[2*NN_ + n];
        #pragma unroll
        for (int t = 0; t < 12; ++t) {
            float ru = xr[t]*u30 + xr[12+t]*u31 + xr[24+t]*u32;
            lM[t]    += u20 * ru;
            lM[12+t] += u21 * ru;
            lM[24+t] += u22 * ru;
            lA[t]    += xr[t]    * u1;
            lA[12+t] += xr[12+t] * u1;
            lA[24+t] += xr[24+t] * u1;
        }
    }
    __shared__ float pA[4][36], pM[4][36];
    __shared__ float tA[36], tM[36], sgs[144], es[144], cmax[12], csum[12];
    #pragma unroll
    for (int i = 0; i < 36; ++i) {
        float v = wave_reduce_sum(lA[i]);
        if (lane == 0) pA[wid][i] = v;
        float w = wave_reduce_sum(lM[i]);
        if (lane == 0) pM[wid][i] = w;
    }
    __syncthreads();
    if (tid < 36) tA[tid] = pA[0][tid] + pA[1][tid] + pA[2][tid] + pA[3][tid];
    else if (tid < 72) {
        int i = tid - 36;
        tM[i] = pM[0][i] + pM[1][i] + pM[2][i] + pM[3][i];
    }
    __syncthreads();
    if (tid < 144) {
        int t = tid / 12, u = tid % 12;
        float p = tA[t]*tM[u] + tA[12+t]*tM[12+u] + tA[24+t]*tM[24+u];
        p += be[tid];
        sgs[tid] = 1.f / (1.f + expf(-p));
    }
    __syncthreads();
    if (tid < 144) {
        int i = tid / 12, j = tid % 12;
        float e = 0.f;
        #pragma unroll
        for (int k = 0; k < 12; ++k) e += sgs[i*12 + k] * Ve[j*12 + k];
        es[tid] = e;
    }
    __syncthreads();
    if (tid < 12) {
        int j = tid;
        float m = -1e30f;
        for (int i = 0; i < 12; ++i) m = fmaxf(m, es[i*12 + j]);
        float sx = 0.f;
        for (int i = 0; i < 12; ++i) sx += expf(es[i*12 + j] - m);
        cmax[j] = m; csum[j] = sx;
    }
    __syncthreads();
    if (tid < 144) {
        int j = tid % 12;
        tat[(size_t)b*144 + tid] = expf(es[tid] - cmax[j]) / csum[j];
    }
}

// ---------------- x_tat projections -> lhsT (B,N,T), rhs2 (B,T,N) ----------------
__global__ __launch_bounds__(256) void k_xtat(
    const float* __restrict__ x, const float* __restrict__ tat,
    const float* __restrict__ W1, const float* __restrict__ W2,
    const float* __restrict__ W3,
    float* __restrict__ lhsT, float* __restrict__ rhs2)
{
    const int id = blockIdx.x * 256 + threadIdx.x;
    const int b = id >> 10, n = id & 1023;
    const float* xp = x + (size_t)id * 36;
    float xr[36];
    #pragma unroll
    for (int i = 0; i < 9; ++i) *(float4*)&xr[i*4] = *(const float4*)(xp + i*4);
    const float* tp = tat + (size_t)b * 144;
    float xt[36];
    #pragma unroll
    for (int f = 0; f < 3; ++f)
        #pragma unroll
        for (int u = 0; u < 12; ++u) {
            float s = 0.f;
            #pragma unroll
            for (int t = 0; t < 12; ++t) s += xr[f*12 + t] * tp[t*12 + u];
            xt[f*12 + u] = s;
        }
    float lA0 = 0.f, lA1 = 0.f, lA2 = 0.f;
    #pragma unroll
    for (int t = 0; t < 12; ++t) {
        float w = W1[t];
        lA0 += xt[t]*w; lA1 += xt[12+t]*w; lA2 += xt[24+t]*w;
    }
    #pragma unroll
    for (int t2 = 0; t2 < 12; ++t2)
        lhsT[(size_t)id*12 + t2] = lA0*W2[t2] + lA1*W2[12+t2] + lA2*W2[24+t2];
    const float w30 = W3[0], w31 = W3[1], w32 = W3[2];
    #pragma unroll
    for (int u = 0; u < 12; ++u)
        rhs2[((size_t)b*12 + u)*NN_ + n] = xt[u]*w30 + xt[12+u]*w31 + xt[24+u]*w32;
}

// ---------------- sig2 (B,N,N) -> bf16 ----------------
__global__ __launch_bounds__(256) void k_sig2(
    const float* __restrict__ lhsT, const float* __restrict__ rhs2,
    const float* __restrict__ bs, __hip_bfloat16* __restrict__ sig2b)
{
    const unsigned int idx = blockIdx.x * 256u + threadIdx.x;
    const int m = (int)(idx & 1023u);
    const unsigned int bn = idx >> 10;
    const int b = (int)(bn >> 10);
    const int n = (int)(bn & 1023u);
    const float* lp = lhsT + (size_t)bn * 12;
    const float* rp = rhs2 + (size_t)b * 12 * NN_ + m;
    float z = bs[(size_t)n * NN_ + m];
    #pragma unroll
    for (int t = 0; t < 12; ++t) z += lp[t] * rp[(size_t)t * NN_];
    sig2b[idx] = __float2bfloat16(1.f / (1.f + expf(-z)));
}

// ---------------- fp32 -> bf16 converters ----------------
__global__ __launch_bounds__(256) void k_cvt4(
    const float* __restrict__ src, unsigned short* __restrict__ dst)
{
    const int i = blockIdx.x * 256 + threadIdx.x;
    float4 v = ((const float4*)src)[i];
    ushort4 o;
    o.x = f2b(v.x); o.y = f2b(v.y); o.z = f2b(v.z); o.w = f2b(v.w);
    ((ushort4*)dst)[i] = o;
}

// ---------------- S = sig2 @ Vs^T, fused exp + colsum; store expS bf16 ----------------
__global__ __launch_bounds__(256) void k_gemm_s_mfma(
    const short* __restrict__ A,   // sig2b [B][1024][1024] bf16
    const short* __restrict__ Bm,  // Vsb   [1024][1024] bf16
    unsigned short* __restrict__ E, // expS bf16 out
    float* __restrict__ colsum)
{
    __shared__ short As[128 * 32];
    __shared__ short Bs[128 * 32];
    const int b  = blockIdx.z;
    const int i0 = blockIdx.y * 128;
    const int j0 = blockIdx.x * 128;
    const int tid = threadIdx.x;
    const int wid = tid >> 6;
    const int lane = tid & 63;
    const int wr = wid & 1, wc = wid >> 1;
    const short* Ab = A + (size_t)b * NN_ * NN_;

    f32x4 acc[4][4];
    const f32x4 z4 = {0.f, 0.f, 0.f, 0.f};
    #pragma unroll
    for (int m = 0; m < 4; ++m)
        #pragma unroll
        for (int n = 0; n < 4; ++n) acc[m][n] = z4;

    const int srow = lane >> 2;
    const int schk = lane & 3;
    const int fr = lane & 15;
    const int kb = (lane >> 4) * 8;

    for (int k0 = 0; k0 < NN_; k0 += 32) {
        #pragma unroll
        for (int q = 0; q < 2; ++q) {
            const int rb = (wid * 2 + q) * 16;
            const short* srcA = Ab + (size_t)(i0 + rb + srow) * NN_ + k0 + schk * 8;
            const short* srcB = Bm + (size_t)(j0 + rb + srow) * NN_ + k0 + schk * 8;
            __builtin_amdgcn_global_load_lds(
                (const __attribute__((address_space(1))) unsigned int*)srcA,
                (__attribute__((address_space(3))) unsigned int*)(As + rb * 32), 16, 0, 0);
            __builtin_amdgcn_global_load_lds(
                (const __attribute__((address_space(1))) unsigned int*)srcB,
                (__attribute__((address_space(3))) unsigned int*)(Bs + rb * 32), 16, 0, 0);
        }
        __syncthreads();
        bf16x8 aF[4], bF[4];
        #pragma unroll
        for (int m = 0; m < 4; ++m)
            aF[m] = *(const bf16x8*)(As + (wr*64 + m*16 + fr) * 32 + kb);
        #pragma unroll
        for (int n = 0; n < 4; ++n)
            bF[n] = *(const bf16x8*)(Bs + (wc*64 + n*16 + fr) * 32 + kb);
        #pragma unroll
        for (int m = 0; m < 4; ++m)
            #pragma unroll
            for (int n = 0; n < 4; ++n)
                acc[m][n] = __builtin_amdgcn_mfma_f32_16x16x32_bf16(aF[m], bF[n], acc[m][n], 0, 0, 0);
        __syncthreads();
    }
    unsigned short* Ep = E + (size_t)b * NN_ * NN_;
    const int cn = lane & 15;
    const int r0 = (lane >> 4) * 4;
    float cs[4] = {0.f, 0.f, 0.f, 0.f};
    #pragma unroll
    for (int m = 0; m < 4; ++m)
        #pragma unroll
        for (int n = 0; n < 4; ++n)
            #pragma unroll
            for (int r = 0; r < 4; ++r) {
                float e = __expf(acc[m][n][r]);
                Ep[(size_t)(i0 + wr*64 + m*16 + r0 + r) * NN_ + j0 + wc*64 + n*16 + cn] = f2b(e);
                cs[n] += e;
            }
    #pragma unroll
    for (int n = 0; n < 4; ++n) {
        float s = cs[n];
        s += __shfl_xor(s, 16);
        s += __shfl_xor(s, 32);
        if (lane < 16)
            atomicAdd(&colsum[b * NN_ + j0 + wc*64 + n*16 + cn], s);
    }
}

// ---- rhs_c partial[z][b,k,m,f,t] = sum_{n in half z} chebb[k,n,m]*expS[b,n,m]*rcs[m]*x[b,n,f,t] ----
__global__ __launch_bounds__(256) void k_rhsc(
    const unsigned short* __restrict__ chebb, const unsigned short* __restrict__ expS,
    const float* __restrict__ colsum, const float* __restrict__ x,
    float* __restrict__ rhsc)
{
    __shared__ float ch[3][16][64];
    __shared__ float st[16][64];
    __shared__ float xs[16][36];
    const int m0 = blockIdx.x * 64;
    const int b  = blockIdx.y;
    const int z  = blockIdx.z;
    const int nbase = z * 512;
    const int tid = threadIdx.x;
    const int m = tid >> 2, q = tid & 3;
    const int nn = tid >> 4, mm = (tid & 15) << 2;
    float4 rcs;
    {
        const float* cp = colsum + b * NN_ + m0 + mm;
        rcs.x = 1.f / cp[0]; rcs.y = 1.f / cp[1];
        rcs.z = 1.f / cp[2]; rcs.w = 1.f / cp[3];
    }
    float acc[3][9];
    #pragma unroll
    for (int k = 0; k < 3; ++k)
        #pragma unroll
        for (int jj = 0; jj < 9; ++jj) acc[k][jj] = 0.f;

    const unsigned short* sb = expS + (size_t)b * NN_ * NN_;
    const float* xb = x + (size_t)b * NN_ * 36;
    for (int n0 = nbase; n0 < nbase + 512; n0 += 16) {
        #pragma unroll
        for (int k = 0; k < 3; ++k) {
            ushort4 u = *(const ushort4*)(chebb + (size_t)k * NN_ * NN_ + (size_t)(n0 + nn) * NN_ + m0 + mm);
            ch[k][nn][mm+0] = b2f(u.x); ch[k][nn][mm+1] = b2f(u.y);
            ch[k][nn][mm+2] = b2f(u.z); ch[k][nn][mm+3] = b2f(u.w);
        }
        {
            ushort4 u = *(const ushort4*)(sb + (size_t)(n0 + nn) * NN_ + m0 + mm);
            st[nn][mm+0] = b2f(u.x) * rcs.x; st[nn][mm+1] = b2f(u.y) * rcs.y;
            st[nn][mm+2] = b2f(u.z) * rcs.z; st[nn][mm+3] = b2f(u.w) * rcs.w;
        }
        if (tid < 144) {
            int n2 = tid / 9, q2 = tid - n2 * 9;
            *(float4*)&xs[n2][q2*4] = *(const float4*)(xb + (size_t)(n0 + n2) * 36 + q2*4);
        }
        __syncthreads();
        #pragma unroll
        for (int u = 0; u < 16; ++u) {
            float xv[9];
            #pragma unroll
            for (int jj = 0; jj < 9; ++jj) xv[jj] = xs[u][q*9 + jj];
            const float sv = st[u][m];
            #pragma unroll
            for (int k = 0; k < 3; ++k) {
                const float w = ch[k][u][m] * sv;
                #pragma unroll
                for (int jj = 0; jj < 9; ++jj) acc[k][jj] += w * xv[jj];
            }
        }
        __syncthreads();
    }
    #pragma unroll
    for (int k = 0; k < 3; ++k) {
        float* rp = rhsc + (size_t)z * 1769472 + (((size_t)b*3 + k) * NN_ + m0 + m) * 36 + q*9;
        #pragma unroll
        for (int jj = 0; jj < 9; ++jj) rp[jj] = acc[k][jj];
    }
}

// ---- fused gcn + tconv-as-3-shifted-GEMMs + residual + relu + stats -> y ----
#define G2S 72            // Gs2 row stride (halfwords): 64 + 8 pad
#define RSTR 112          // Rs item stride (floats): 108 + 4 pad
__global__ __launch_bounds__(256) void k_y6(
    const float* __restrict__ rhsc0, const float* __restrict__ rhsc1,
    const unsigned short* __restrict__ WtG,
    const float* __restrict__ Theta, const float* __restrict__ x,
    const float* __restrict__ tcb,
    const float* __restrict__ rcw, const float* __restrict__ rcb,
    float* __restrict__ y, float* __restrict__ acc)
{
    __shared__ unsigned short Gs2[193 * G2S];   // 27.8 KB (row 192 = zeros)
    __shared__ float Rs[16 * RSTR];             // 7.2 KB
    __shared__ float xls[16 * 36];              // 2.25 KB
    const int tid = threadIdx.x;
    const int wid = tid >> 6, lane = tid & 63;
    const int blk = blockIdx.x;                 // items blk*16 .. +15

    // ---- stage Rs = rhsc0 + rhsc1, coalesced float4 ----
    const int bb = (blk * 16) >> 10;
    const int nb = (blk * 16) & 1023;
    for (int idx = tid; idx < 432; idx += 256) {
        const int i = idx / 27;
        const int r = idx - i * 27;
        const int k = r / 9;
        const int q = r - k * 9;
        const size_t off = (((size_t)bb * 3 + k) * NN_ + nb + i) * 36 + q * 4;
        float4 a = *(const float4*)(rhsc0 + off);
        float4 b = *(const float4*)(rhsc1 + off);
        a.x += b.x; a.y += b.y; a.z += b.z; a.w += b.w;
        *(float4*)&Rs[i * RSTR + k * 36 + q * 4] = a;
    }
    // zero row for t-boundary
    if (tid < 36) ((unsigned int*)(Gs2 + 192 * G2S))[tid] = 0u;
    if (tid < 144)
        ((float4*)xls)[tid] = ((const float4*)(x + (size_t)blk * 16 * 36))[tid];
    __syncthreads();

    // ---- phase 1: gcn -> Gs2[nt][cp]. wave wid: items 4*wid..+3, lane = cp ----
    {
        float th[9];
        #pragma unroll
        for (int j = 0; j < 9; ++j) th[j] = Theta[j * 64 + lane];
        #pragma unroll
        for (int ii = 0; ii < 4; ++ii) {
            const int i = wid * 4 + ii;
            float g[12];
            #pragma unroll
            for (int t = 0; t < 12; ++t) g[t] = 0.f;
            #pragma unroll
            for (int kf = 0; kf < 9; ++kf) {
                const float* rp = Rs + i * RSTR + kf * 12;
                float4 v0 = *(const float4*)(rp);
                float4 v1 = *(const float4*)(rp + 4);
                float4 v2 = *(const float4*)(rp + 8);
                const float w = th[kf];
                g[0] += v0.x*w; g[1] += v0.y*w; g[2]  += v0.z*w; g[3]  += v0.w*w;
                g[4] += v1.x*w; g[5] += v1.y*w; g[6]  += v1.z*w; g[7]  += v1.w*w;
                g[8] += v2.x*w; g[9] += v2.y*w; g[10] += v2.z*w; g[11] += v2.w*w;
            }
            #pragma unroll
            for (int t = 0; t < 12; ++t)
                Gs2[(i*12 + t) * G2S + lane] = f2b(fmaxf(g[t], 0.f));
        }
    }
    __syncthreads();

    // ---- phase 2: 3 shifted GEMMs; wave wid -> c-tile; 72 MFMA/wave ----
    const int cl = lane & 15, kg = lane >> 4;
    const int c = wid * 16 + cl;
    bf16x8 bW[3][2];
    #pragma unroll
    for (int d = 0; d < 3; ++d)
        #pragma unroll
        for (int kb = 0; kb < 2; ++kb)
            bW[d][kb] = *(const bf16x8*)(WtG + (d*64 + c) * 64 + kb*32 + kg*8);
    const float tb = tcb[c];
    const float rw0 = rcw[c*3], rw1 = rcw[c*3+1], rw2 = rcw[c*3+2];
    const float rbv = rcb[c];
    float ls = 0.f, lss = 0.f;
    #pragma unroll
    for (int rt = 0; rt < 12; ++rt) {
        const int nt = rt * 16 + cl;
        const int t = nt - (nt / 12) * 12;
        const unsigned short* g1 = Gs2 + nt * G2S + kg * 8;
        const unsigned short* g0 = (t == 0)  ? (Gs2 + 192 * G2S + kg * 8) : (g1 - G2S);
        const unsigned short* g2 = (t == 11) ? (Gs2 + 192 * G2S + kg * 8) : (g1 + G2S);
        f32x4 a4 = {0.f, 0.f, 0.f, 0.f};
        #pragma unroll
        for (int kb = 0; kb < 2; ++kb) {
            a4 = __builtin_amdgcn_mfma_f32_16x16x32_bf16(*(const bf16x8*)(g0 + kb*32), bW[0][kb], a4, 0, 0, 0);
            a4 = __builtin_amdgcn_mfma_f32_16x16x32_bf16(*(const bf16x8*)(g1 + kb*32), bW[1][kb], a4, 0, 0, 0);
            a4 = __builtin_amdgcn_mfma_f32_16x16x32_bf16(*(const bf16x8*)(g2 + kb*32), bW[2][kb], a4, 0, 0, 0);
        }
        #pragma unroll
        for (int r = 0; r < 4; ++r) {
            const int nto = rt * 16 + kg * 4 + r;
            const int i = nto / 12;
            const int tt = nto - i * 12;
            const float xres = rbv + xls[i*36 + tt]*rw0 + xls[i*36 + 12 + tt]*rw1 + xls[i*36 + 24 + tt]*rw2;
            const float v = fmaxf(xres + a4[r] + tb, 0.f);
            ls += v; lss += v * v;
            y[(size_t)(blk*16 + i) * 768 + c * 12 + tt] = v;
        }
    }
    ls  = wave_reduce_sum(ls);
    lss = wave_reduce_sum(lss);
    if (lane == 0) { atomicAdd(&acc[0], ls); atomicAdd(&acc[1], lss); }
}

// ---------------- finalize mean / inv_std ----------------
__global__ void k_fin(float* __restrict__ acc) {
    const float cnt = (float)((size_t)BB * NN_ * 64 * TT);
    float mu = acc[0] / cnt;
    float var = acc[1] / cnt - mu * mu;
    acc[2] = mu;
    acc[3] = rsqrtf(var + 1e-5f);
}

// ---------------- normalize in place on d_out ----------------
__global__ __launch_bounds__(256) void k_norm(
    float* __restrict__ y, const float* __restrict__ lng,
    const float* __restrict__ lnb, const float* __restrict__ acc)
{
    const unsigned int i = blockIdx.x * 256u + threadIdx.x;
    const float mu = acc[2], inv = acc[3];
    float4 v  = ((const float4*)y)[i];
    float4 gv = ((const float4*)lng)[i];
    float4 bv = ((const float4*)lnb)[i];
    v.x = (v.x - mu) * inv * gv.x + bv.x;
    v.y = (v.y - mu) * inv * gv.y + bv.y;
    v.z = (v.z - mu) * inv * gv.z + bv.z;
    v.w = (v.w - mu) * inv * gv.w + bv.w;
    ((float4*)y)[i] = v;
}

extern "C" void kernel_launch(void* const* d_in, const int* in_sizes, int n_in,
                              void* d_out, int out_size, void* d_ws, size_t ws_size,
                              hipStream_t stream)
{
    const float* x    = (const float*)d_in[0];
    const float* U1   = (const float*)d_in[1];
    const float* U2   = (const float*)d_in[2];
    const float* U3   = (const float*)d_in[3];
    const float* be   = (const float*)d_in[4];
    const float* Ve   = (const float*)d_in[5];
    const float* W1   = (const float*)d_in[6];
    const float* W2   = (const float*)d_in[7];
    const float* W3   = (const float*)d_in[8];
    const float* bs   = (const float*)d_in[9];
    const float* Vs   = (const float*)d_in[10];
    const float* cheb = (const float*)d_in[11];
    const float* Th   = (const float*)d_in[12];
    const float* tcw  = (const float*)d_in[13];
    const float* tcb  = (const float*)d_in[14];
    const float* rcw  = (const float*)d_in[15];
    const float* rcb  = (const float*)d_in[16];
    const float* lng  = (const float*)d_in[17];
    const float* lnb  = (const float*)d_in[18];
    float* out = (float*)d_out;
    float* ws  = (float*)d_ws;

    float* acc    = ws + ACC_OFF;
    float* colsum = ws + COLSUM_OFF;
    float* tat    = ws + TAT_OFF;
    float* lhsT   = ws + LHST_OFF;
    float* rhs2   = ws + RHS2_OFF;
    unsigned short* Vsb   = (unsigned short*)(ws + VSB_OFF);
    unsigned short* sig2b = (unsigned short*)(ws + SIG2B_OFF);
    unsigned short* chebb = (unsigned short*)(ws + CHEBB_OFF);
    unsigned short* expS  = (unsigned short*)(ws + EXPS_OFF);
    float* rhsc0  = ws + RHSC0_OFF;
    float* rhsc1  = ws + RHSC1_OFF;
    unsigned short* WtG   = (unsigned short*)(ws + WTG_OFF);

    k_init<<<65, 256, 0, stream>>>(ws);
    k_cvtw<<<1, 256, 0, stream>>>(tcw, WtG);
    k_temporal<<<BB, 256, 0, stream>>>(x, U1, U2, U3, be, Ve, tat);
    k_xtat<<<(BB * NN_) / 256, 256, 0, stream>>>(x, tat, W1, W2, W3, lhsT, rhs2);
    k_cvt4<<<(NN_ * NN_) / 1024, 256, 0, stream>>>(Vs, Vsb);
    k_cvt4<<<(3 * NN_ * NN_) / 1024, 256, 0, stream>>>(cheb, chebb);
    k_sig2<<<(BB * NN_ * NN_) / 256, 256, 0, stream>>>(lhsT, rhs2, bs, (__hip_bfloat16*)sig2b);
    k_gemm_s_mfma<<<dim3(8, 8, BB), 256, 0, stream>>>((const short*)sig2b, (const short*)Vsb, expS, colsum);
    k_rhsc<<<dim3(16, BB, 2), 256, 0, stream>>>(chebb, expS, colsum, x, rhsc0);
    k_y6<<<(BB * NN_) / 16, 256, 0, stream>>>(rhsc0, rhsc1, WtG, Th, x, tcb, rcw, rcb, out, acc);
    k_fin<<<1, 1, 0, stream>>>(acc);
    k_norm<<<(BB * NN_ * 64 * TT) / 4 / 256, 256, 0, stream>>>(out, lng, lnb, acc);
}

// Round 7
// 443.911 us; speedup vs baseline: 1.2239x; 1.2239x over previous
//
#include <hip/hip_runtime.h>
#include <hip/hip_bf16.h>
#include <math.h>

#define BB 16
#define NN_ 1024
#define TT 12

typedef __attribute__((ext_vector_type(8))) short bf16x8;
typedef __attribute__((ext_vector_type(4))) float f32x4;

// ---------------- workspace layout (float units) ----------------
static const size_t ACC_OFF    = 0;          // 16
static const size_t COLSUM_OFF = 16;         // B*N = 16384
static const size_t TAT_OFF    = 16400;      // B*T*T = 2304
static const size_t LHST_OFF   = 18704;      // B*N*T = 196608
static const size_t RHS2_OFF   = 215312;     // B*T*N = 196608
static const size_t VSB_OFF    = 411920;     // N*N bf16 = 524288 floats
static const size_t SIG2B_OFF  = 936208;     // B*N*N bf16 = 8388608 floats
static const size_t CHEBB_OFF  = 9324816;    // 3*N*N bf16 = 1572864 floats
static const size_t EXPS_OFF   = 10897680;   // B*N*N bf16 = 8388608 floats
static const size_t RHSC0_OFF  = 19286288;   // B*K*N*F*T fp32 = 1769472
static const size_t RHSC1_OFF  = 21055760;   // B*K*N*F*T fp32 = 1769472
static const size_t WTG_OFF    = 22825232;   // 192*64 bf16 = 6144 floats
static const size_t PART_OFF   = 22831376;   // 2048 floats (block partial sums)
// total 22833424 floats = ~91 MB

__device__ __forceinline__ float wave_reduce_sum(float v) {
    #pragma unroll
    for (int off = 32; off > 0; off >>= 1) v += __shfl_down(v, off);
    return v;
}

__device__ __forceinline__ unsigned short f2b(float f) {
    __hip_bfloat16 h = __float2bfloat16(f);
    return *(unsigned short*)&h;
}
__device__ __forceinline__ float b2f(unsigned short u) {
    return __uint_as_float(((unsigned int)u) << 16);
}

// ---------------- init: zero acc + colsum ----------------
__global__ void k_init(float* __restrict__ ws) {
    int i = blockIdx.x * 256 + threadIdx.x;
    if (i < 16400) ws[i] = 0.f;
}

// ---------------- tcw -> WtG[d*64+c][cp] bf16 (one block) ----------------
__global__ __launch_bounds__(256) void k_cvtw(
    const float* __restrict__ tcw, unsigned short* __restrict__ WtG)
{
    for (int j = threadIdx.x; j < 12288; j += 256) {
        const int row = j >> 6;            // d*64 + c
        const int cp  = j & 63;
        const int d   = row >> 6;
        const int c   = row & 63;
        WtG[j] = f2b(tcw[c * 192 + 3 * cp + d]);
    }
}

// ---------------- temporal attention -> tat (B,T,T), 256 threads ----------------
__global__ __launch_bounds__(256) void k_temporal(
    const float* __restrict__ x, const float* __restrict__ U1,
    const float* __restrict__ U2, const float* __restrict__ U3,
    const float* __restrict__ be, const float* __restrict__ Ve,
    float* __restrict__ tat)
{
    const int b = blockIdx.x;
    const int tid = threadIdx.x;
    const int wid = tid >> 6, lane = tid & 63;
    float lA[36], lM[36];
    #pragma unroll
    for (int i = 0; i < 36; ++i) { lA[i] = 0.f; lM[i] = 0.f; }
    const float u30 = U3[0], u31 = U3[1], u32 = U3[2];
    for (int n = tid; n < NN_; n += 256) {
        const float* xp = x + ((size_t)b * NN_ + n) * 36;
        float xr[36];
        #pragma unroll
        for (int i = 0; i < 9; ++i) *(float4*)&xr[i*4] = *(const float4*)(xp + i*4);
        const float u1  = U1[n];
        const float u20 = U2[n], u21 = U2[NN_ + n], u22 = U2[2*NN_ + n];
        #pragma unroll
        for (int t = 0; t < 12; ++t) {
            float ru = xr[t]*u30 + xr[12+t]*u31 + xr[24+t]*u32;
            lM[t]    += u20 * ru;
            lM[12+t] += u21 * ru;
            lM[24+t] += u22 * ru;
            lA[t]    += xr[t]    * u1;
            lA[12+t] += xr[12+t] * u1;
            lA[24+t] += xr[24+t] * u1;
        }
    }
    __shared__ float pA[4][36], pM[4][36];
    __shared__ float tA[36], tM[36], sgs[144], es[144], cmax[12], csum[12];
    #pragma unroll
    for (int i = 0; i < 36; ++i) {
        float v = wave_reduce_sum(lA[i]);
        if (lane == 0) pA[wid][i] = v;
        float w = wave_reduce_sum(lM[i]);
        if (lane == 0) pM[wid][i] = w;
    }
    __syncthreads();
    if (tid < 36) tA[tid] = pA[0][tid] + pA[1][tid] + pA[2][tid] + pA[3][tid];
    else if (tid < 72) {
        int i = tid - 36;
        tM[i] = pM[0][i] + pM[1][i] + pM[2][i] + pM[3][i];
    }
    __syncthreads();
    if (tid < 144) {
        int t = tid / 12, u = tid % 12;
        float p = tA[t]*tM[u] + tA[12+t]*tM[12+u] + tA[24+t]*tM[24+u];
        p += be[tid];
        sgs[tid] = 1.f / (1.f + expf(-p));
    }
    __syncthreads();
    if (tid < 144) {
        int i = tid / 12, j = tid % 12;
        float e = 0.f;
        #pragma unroll
        for (int k = 0; k < 12; ++k) e += sgs[i*12 + k] * Ve[j*12 + k];
        es[tid] = e;
    }
    __syncthreads();
    if (tid < 12) {
        int j = tid;
        float m = -1e30f;
        for (int i = 0; i < 12; ++i) m = fmaxf(m, es[i*12 + j]);
        float sx = 0.f;
        for (int i = 0; i < 12; ++i) sx += expf(es[i*12 + j] - m);
        cmax[j] = m; csum[j] = sx;
    }
    __syncthreads();
    if (tid < 144) {
        int j = tid % 12;
        tat[(size_t)b*144 + tid] = expf(es[tid] - cmax[j]) / csum[j];
    }
}

// ---------------- x_tat projections -> lhsT (B,N,T), rhs2 (B,T,N) ----------------
__global__ __launch_bounds__(256) void k_xtat(
    const float* __restrict__ x, const float* __restrict__ tat,
    const float* __restrict__ W1, const float* __restrict__ W2,
    const float* __restrict__ W3,
    float* __restrict__ lhsT, float* __restrict__ rhs2)
{
    const int id = blockIdx.x * 256 + threadIdx.x;
    const int b = id >> 10, n = id & 1023;
    const float* xp = x + (size_t)id * 36;
    float xr[36];
    #pragma unroll
    for (int i = 0; i < 9; ++i) *(float4*)&xr[i*4] = *(const float4*)(xp + i*4);
    const float* tp = tat + (size_t)b * 144;
    float xt[36];
    #pragma unroll
    for (int f = 0; f < 3; ++f)
        #pragma unroll
        for (int u = 0; u < 12; ++u) {
            float s = 0.f;
            #pragma unroll
            for (int t = 0; t < 12; ++t) s += xr[f*12 + t] * tp[t*12 + u];
            xt[f*12 + u] = s;
        }
    float lA0 = 0.f, lA1 = 0.f, lA2 = 0.f;
    #pragma unroll
    for (int t = 0; t < 12; ++t) {
        float w = W1[t];
        lA0 += xt[t]*w; lA1 += xt[12+t]*w; lA2 += xt[24+t]*w;
    }
    #pragma unroll
    for (int t2 = 0; t2 < 12; ++t2)
        lhsT[(size_t)id*12 + t2] = lA0*W2[t2] + lA1*W2[12+t2] + lA2*W2[24+t2];
    const float w30 = W3[0], w31 = W3[1], w32 = W3[2];
    #pragma unroll
    for (int u = 0; u < 12; ++u)
        rhs2[((size_t)b*12 + u)*NN_ + n] = xt[u]*w30 + xt[12+u]*w31 + xt[24+u]*w32;
}

// ---------------- sig2 (B,N,N) -> bf16 ----------------
__global__ __launch_bounds__(256) void k_sig2(
    const float* __restrict__ lhsT, const float* __restrict__ rhs2,
    const float* __restrict__ bs, __hip_bfloat16* __restrict__ sig2b)
{
    const unsigned int idx = blockIdx.x * 256u + threadIdx.x;
    const int m = (int)(idx & 1023u);
    const unsigned int bn = idx >> 10;
    const int b = (int)(bn >> 10);
    const int n = (int)(bn & 1023u);
    const float* lp = lhsT + (size_t)bn * 12;
    const float* rp = rhs2 + (size_t)b * 12 * NN_ + m;
    float z = bs[(size_t)n * NN_ + m];
    #pragma unroll
    for (int t = 0; t < 12; ++t) z += lp[t] * rp[(size_t)t * NN_];
    sig2b[idx] = __float2bfloat16(1.f / (1.f + expf(-z)));
}

// ---------------- fp32 -> bf16 converters ----------------
__global__ __launch_bounds__(256) void k_cvt4(
    const float* __restrict__ src, unsigned short* __restrict__ dst)
{
    const int i = blockIdx.x * 256 + threadIdx.x;
    float4 v = ((const float4*)src)[i];
    ushort4 o;
    o.x = f2b(v.x); o.y = f2b(v.y); o.z = f2b(v.z); o.w = f2b(v.w);
    ((ushort4*)dst)[i] = o;
}

// ---------------- S = sig2 @ Vs^T, fused exp + colsum; store expS bf16 ----------------
__global__ __launch_bounds__(256) void k_gemm_s_mfma(
    const short* __restrict__ A,   // sig2b [B][1024][1024] bf16
    const short* __restrict__ Bm,  // Vsb   [1024][1024] bf16
    unsigned short* __restrict__ E, // expS bf16 out
    float* __restrict__ colsum)
{
    __shared__ short As[128 * 32];
    __shared__ short Bs[128 * 32];
    const int b  = blockIdx.z;
    const int i0 = blockIdx.y * 128;
    const int j0 = blockIdx.x * 128;
    const int tid = threadIdx.x;
    const int wid = tid >> 6;
    const int lane = tid & 63;
    const int wr = wid & 1, wc = wid >> 1;
    const short* Ab = A + (size_t)b * NN_ * NN_;

    f32x4 acc[4][4];
    const f32x4 z4 = {0.f, 0.f, 0.f, 0.f};
    #pragma unroll
    for (int m = 0; m < 4; ++m)
        #pragma unroll
        for (int n = 0; n < 4; ++n) acc[m][n] = z4;

    const int srow = lane >> 2;
    const int schk = lane & 3;
    const int fr = lane & 15;
    const int kb = (lane >> 4) * 8;

    for (int k0 = 0; k0 < NN_; k0 += 32) {
        #pragma unroll
        for (int q = 0; q < 2; ++q) {
            const int rb = (wid * 2 + q) * 16;
            const short* srcA = Ab + (size_t)(i0 + rb + srow) * NN_ + k0 + schk * 8;
            const short* srcB = Bm + (size_t)(j0 + rb + srow) * NN_ + k0 + schk * 8;
            __builtin_amdgcn_global_load_lds(
                (const __attribute__((address_space(1))) unsigned int*)srcA,
                (__attribute__((address_space(3))) unsigned int*)(As + rb * 32), 16, 0, 0);
            __builtin_amdgcn_global_load_lds(
                (const __attribute__((address_space(1))) unsigned int*)srcB,
                (__attribute__((address_space(3))) unsigned int*)(Bs + rb * 32), 16, 0, 0);
        }
        __syncthreads();
        bf16x8 aF[4], bF[4];
        #pragma unroll
        for (int m = 0; m < 4; ++m)
            aF[m] = *(const bf16x8*)(As + (wr*64 + m*16 + fr) * 32 + kb);
        #pragma unroll
        for (int n = 0; n < 4; ++n)
            bF[n] = *(const bf16x8*)(Bs + (wc*64 + n*16 + fr) * 32 + kb);
        #pragma unroll
        for (int m = 0; m < 4; ++m)
            #pragma unroll
            for (int n = 0; n < 4; ++n)
                acc[m][n] = __builtin_amdgcn_mfma_f32_16x16x32_bf16(aF[m], bF[n], acc[m][n], 0, 0, 0);
        __syncthreads();
    }
    unsigned short* Ep = E + (size_t)b * NN_ * NN_;
    const int cn = lane & 15;
    const int r0 = (lane >> 4) * 4;
    float cs[4] = {0.f, 0.f, 0.f, 0.f};
    #pragma unroll
    for (int m = 0; m < 4; ++m)
        #pragma unroll
        for (int n = 0; n < 4; ++n)
            #pragma unroll
            for (int r = 0; r < 4; ++r) {
                float e = __expf(acc[m][n][r]);
                Ep[(size_t)(i0 + wr*64 + m*16 + r0 + r) * NN_ + j0 + wc*64 + n*16 + cn] = f2b(e);
                cs[n] += e;
            }
    #pragma unroll
    for (int n = 0; n < 4; ++n) {
        float s = cs[n];
        s += __shfl_xor(s, 16);
        s += __shfl_xor(s, 32);
        if (lane < 16)
            atomicAdd(&colsum[b * NN_ + j0 + wc*64 + n*16 + cn], s);
    }
}

// ---- rhs_c partial[z][b,k,m,f,t] = sum_{n in half z} chebb[k,n,m]*expS[b,n,m]*rcs[m]*x[b,n,f,t] ----
__global__ __launch_bounds__(256) void k_rhsc(
    const unsigned short* __restrict__ chebb, const unsigned short* __restrict__ expS,
    const float* __restrict__ colsum, const float* __restrict__ x,
    float* __restrict__ rhsc)
{
    __shared__ float ch[3][16][64];
    __shared__ float st[16][64];
    __shared__ float xs[16][36];
    const int m0 = blockIdx.x * 64;
    const int b  = blockIdx.y;
    const int z  = blockIdx.z;
    const int nbase = z * 512;
    const int tid = threadIdx.x;
    const int m = tid >> 2, q = tid & 3;
    const int nn = tid >> 4, mm = (tid & 15) << 2;
    float4 rcs;
    {
        const float* cp = colsum + b * NN_ + m0 + mm;
        rcs.x = 1.f / cp[0]; rcs.y = 1.f / cp[1];
        rcs.z = 1.f / cp[2]; rcs.w = 1.f / cp[3];
    }
    float acc[3][9];
    #pragma unroll
    for (int k = 0; k < 3; ++k)
        #pragma unroll
        for (int jj = 0; jj < 9; ++jj) acc[k][jj] = 0.f;

    const unsigned short* sb = expS + (size_t)b * NN_ * NN_;
    const float* xb = x + (size_t)b * NN_ * 36;
    for (int n0 = nbase; n0 < nbase + 512; n0 += 16) {
        #pragma unroll
        for (int k = 0; k < 3; ++k) {
            ushort4 u = *(const ushort4*)(chebb + (size_t)k * NN_ * NN_ + (size_t)(n0 + nn) * NN_ + m0 + mm);
            ch[k][nn][mm+0] = b2f(u.x); ch[k][nn][mm+1] = b2f(u.y);
            ch[k][nn][mm+2] = b2f(u.z); ch[k][nn][mm+3] = b2f(u.w);
        }
        {
            ushort4 u = *(const ushort4*)(sb + (size_t)(n0 + nn) * NN_ + m0 + mm);
            st[nn][mm+0] = b2f(u.x) * rcs.x; st[nn][mm+1] = b2f(u.y) * rcs.y;
            st[nn][mm+2] = b2f(u.z) * rcs.z; st[nn][mm+3] = b2f(u.w) * rcs.w;
        }
        if (tid < 144) {
            int n2 = tid / 9, q2 = tid - n2 * 9;
            *(float4*)&xs[n2][q2*4] = *(const float4*)(xb + (size_t)(n0 + n2) * 36 + q2*4);
        }
        __syncthreads();
        #pragma unroll
        for (int u = 0; u < 16; ++u) {
            float xv[9];
            #pragma unroll
            for (int jj = 0; jj < 9; ++jj) xv[jj] = xs[u][q*9 + jj];
            const float sv = st[u][m];
            #pragma unroll
            for (int k = 0; k < 3; ++k) {
                const float w = ch[k][u][m] * sv;
                #pragma unroll
                for (int jj = 0; jj < 9; ++jj) acc[k][jj] += w * xv[jj];
            }
        }
        __syncthreads();
    }
    #pragma unroll
    for (int k = 0; k < 3; ++k) {
        float* rp = rhsc + (size_t)z * 1769472 + (((size_t)b*3 + k) * NN_ + m0 + m) * 36 + q*9;
        #pragma unroll
        for (int jj = 0; jj < 9; ++jj) rp[jj] = acc[k][jj];
    }
}

// ---- fused gcn + tconv (3 shifted GEMMs, transposed: out[c][nt]) + residual + relu ----
#define G2S 72            // Gs2 row stride (halfwords): 64 + 8 pad
#define RSTR 112          // Rs item stride (floats): 108 + 4 pad
__global__ __launch_bounds__(256) void k_y7(
    const float* __restrict__ rhsc0, const float* __restrict__ rhsc1,
    const unsigned short* __restrict__ WtG,
    const float* __restrict__ Theta, const float* __restrict__ x,
    const float* __restrict__ tcb,
    const float* __restrict__ rcw, const float* __restrict__ rcb,
    float* __restrict__ y, float* __restrict__ partials)
{
    __shared__ unsigned short Gs2[193 * G2S];   // 27.8 KB (row 192 = zeros)
    __shared__ float Rs[16 * RSTR];             // 7.2 KB
    __shared__ float xls[16 * 36];              // 2.25 KB
    __shared__ float red[8];
    const int tid = threadIdx.x;
    const int wid = tid >> 6, lane = tid & 63;
    const int blk = blockIdx.x;                 // items blk*16 .. +15

    // ---- stage Rs = rhsc0 + rhsc1, coalesced float4 ----
    const int bb = (blk * 16) >> 10;
    const int nb = (blk * 16) & 1023;
    for (int idx = tid; idx < 432; idx += 256) {
        const int i = idx / 27;
        const int r = idx - i * 27;
        const int k = r / 9;
        const int q = r - k * 9;
        const size_t off = (((size_t)bb * 3 + k) * NN_ + nb + i) * 36 + q * 4;
        float4 a = *(const float4*)(rhsc0 + off);
        float4 b = *(const float4*)(rhsc1 + off);
        a.x += b.x; a.y += b.y; a.z += b.z; a.w += b.w;
        *(float4*)&Rs[i * RSTR + k * 36 + q * 4] = a;
    }
    if (tid < 36) ((unsigned int*)(Gs2 + 192 * G2S))[tid] = 0u;
    if (tid < 144)
        ((float4*)xls)[tid] = ((const float4*)(x + (size_t)blk * 16 * 36))[tid];
    __syncthreads();

    // ---- phase 1: gcn -> Gs2[nt][cp]. wave wid: items 4*wid..+3, lane = cp ----
    {
        float th[9];
        #pragma unroll
        for (int j = 0; j < 9; ++j) th[j] = Theta[j * 64 + lane];
        #pragma unroll
        for (int ii = 0; ii < 4; ++ii) {
            const int i = wid * 4 + ii;
            float g[12];
            #pragma unroll
            for (int t = 0; t < 12; ++t) g[t] = 0.f;
            #pragma unroll
            for (int kf = 0; kf < 9; ++kf) {
                const float* rp = Rs + i * RSTR + kf * 12;
                float4 v0 = *(const float4*)(rp);
                float4 v1 = *(const float4*)(rp + 4);
                float4 v2 = *(const float4*)(rp + 8);
                const float w = th[kf];
                g[0] += v0.x*w; g[1] += v0.y*w; g[2]  += v0.z*w; g[3]  += v0.w*w;
                g[4] += v1.x*w; g[5] += v1.y*w; g[6]  += v1.z*w; g[7]  += v1.w*w;
                g[8] += v2.x*w; g[9] += v2.y*w; g[10] += v2.z*w; g[11] += v2.w*w;
            }
            #pragma unroll
            for (int t = 0; t < 12; ++t)
                Gs2[(i*12 + t) * G2S + lane] = f2b(fmaxf(g[t], 0.f));
        }
    }
    __syncthreads();

    // ---- phase 2: out[c][nt], A = W (m=c), B = G (n=nt). Coalesced stores. ----
    const int cl = lane & 15, kg = lane >> 4;
    bf16x8 aW[3][2];
    #pragma unroll
    for (int d = 0; d < 3; ++d)
        #pragma unroll
        for (int kb = 0; kb < 2; ++kb)
            aW[d][kb] = *(const bf16x8*)(WtG + (d*64 + wid*16 + cl) * 64 + kb*32 + kg*8);
    float tb[4], rb[4], rw0[4], rw1[4], rw2[4];
    #pragma unroll
    for (int r = 0; r < 4; ++r) {
        const int c = wid*16 + kg*4 + r;
        tb[r] = tcb[c]; rb[r] = rcb[c];
        rw0[r] = rcw[c*3]; rw1[r] = rcw[c*3+1]; rw2[r] = rcw[c*3+2];
    }
    float ls = 0.f, lss = 0.f;
    #pragma unroll
    for (int ct = 0; ct < 12; ++ct) {
        const int nt = ct * 16 + cl;
        const int i = nt / 12;
        const int t = nt - i * 12;
        const unsigned short* g1 = Gs2 + nt * G2S + kg * 8;
        const unsigned short* g0 = (t == 0)  ? (Gs2 + 192 * G2S + kg * 8) : (g1 - G2S);
        const unsigned short* g2 = (t == 11) ? (Gs2 + 192 * G2S + kg * 8) : (g1 + G2S);
        f32x4 a4 = {0.f, 0.f, 0.f, 0.f};
        #pragma unroll
        for (int kb = 0; kb < 2; ++kb) {
            a4 = __builtin_amdgcn_mfma_f32_16x16x32_bf16(aW[0][kb], *(const bf16x8*)(g0 + kb*32), a4, 0, 0, 0);
            a4 = __builtin_amdgcn_mfma_f32_16x16x32_bf16(aW[1][kb], *(const bf16x8*)(g1 + kb*32), a4, 0, 0, 0);
            a4 = __builtin_amdgcn_mfma_f32_16x16x32_bf16(aW[2][kb], *(const bf16x8*)(g2 + kb*32), a4, 0, 0, 0);
        }
        const float x0 = xls[i*36 + t];
        const float x1 = xls[i*36 + 12 + t];
        const float x2 = xls[i*36 + 24 + t];
        float* yp = y + (size_t)(blk*16 + i) * 768 + (wid*16 + kg*4) * 12 + t;
        #pragma unroll
        for (int r = 0; r < 4; ++r) {
            const float xres = rb[r] + x0*rw0[r] + x1*rw1[r] + x2*rw2[r];
            const float v = fmaxf(xres + a4[r] + tb[r], 0.f);
            ls += v; lss += v * v;
            yp[r * 12] = v;
        }
    }
    ls  = wave_reduce_sum(ls);
    lss = wave_reduce_sum(lss);
    if (lane == 0) { red[wid] = ls; red[4 + wid] = lss; }
    __syncthreads();
    if (tid == 0) {
        partials[blk]        = red[0] + red[1] + red[2] + red[3];
        partials[1024 + blk] = red[4] + red[5] + red[6] + red[7];
    }
}

// ---------------- reduce partials -> mean / inv_std ----------------
__global__ __launch_bounds__(256) void k_fin2(
    const float* __restrict__ partials, float* __restrict__ acc)
{
    const int tid = threadIdx.x;
    const int wid = tid >> 6, lane = tid & 63;
    float s = 0.f, ss = 0.f;
    #pragma unroll
    for (int j = tid; j < 1024; j += 256) {
        s  += partials[j];
        ss += partials[1024 + j];
    }
    s  = wave_reduce_sum(s);
    ss = wave_reduce_sum(ss);
    __shared__ float rs[4], rss[4];
    if (lane == 0) { rs[wid] = s; rss[wid] = ss; }
    __syncthreads();
    if (tid == 0) {
        const float cnt = (float)((size_t)BB * NN_ * 64 * TT);
        float tot  = rs[0] + rs[1] + rs[2] + rs[3];
        float tots = rss[0] + rss[1] + rss[2] + rss[3];
        float mu = tot / cnt;
        float var = tots / cnt - mu * mu;
        acc[2] = mu;
        acc[3] = rsqrtf(var + 1e-5f);
    }
}

// ---------------- normalize in place on d_out ----------------
__global__ __launch_bounds__(256) void k_norm(
    float* __restrict__ y, const float* __restrict__ lng,
    const float* __restrict__ lnb, const float* __restrict__ acc)
{
    const unsigned int i = blockIdx.x * 256u + threadIdx.x;
    const float mu = acc[2], inv = acc[3];
    float4 v  = ((const float4*)y)[i];
    float4 gv = ((const float4*)lng)[i];
    float4 bv = ((const float4*)lnb)[i];
    v.x = (v.x - mu) * inv * gv.x + bv.x;
    v.y = (v.y - mu) * inv * gv.y + bv.y;
    v.z = (v.z - mu) * inv * gv.z + bv.z;
    v.w = (v.w - mu) * inv * gv.w + bv.w;
    ((float4*)y)[i] = v;
}

extern "C" void kernel_launch(void* const* d_in, const int* in_sizes, int n_in,
                              void* d_out, int out_size, void* d_ws, size_t ws_size,
                              hipStream_t stream)
{
    const float* x    = (const float*)d_in[0];
    const float* U1   = (const float*)d_in[1];
    const float* U2   = (const float*)d_in[2];
    const float* U3   = (const float*)d_in[3];
    const float* be   = (const float*)d_in[4];
    const float* Ve   = (const float*)d_in[5];
    const float* W1   = (const float*)d_in[6];
    const float* W2   = (const float*)d_in[7];
    const float* W3   = (const float*)d_in[8];
    const float* bs   = (const float*)d_in[9];
    const float* Vs   = (const float*)d_in[10];
    const float* cheb = (const float*)d_in[11];
    const float* Th   = (const float*)d_in[12];
    const float* tcw  = (const float*)d_in[13];
    const float* tcb  = (const float*)d_in[14];
    const float* rcw  = (const float*)d_in[15];
    const float* rcb  = (const float*)d_in[16];
    const float* lng  = (const float*)d_in[17];
    const float* lnb  = (const float*)d_in[18];
    float* out = (float*)d_out;
    float* ws  = (float*)d_ws;

    float* acc    = ws + ACC_OFF;
    float* colsum = ws + COLSUM_OFF;
    float* tat    = ws + TAT_OFF;
    float* lhsT   = ws + LHST_OFF;
    float* rhs2   = ws + RHS2_OFF;
    unsigned short* Vsb   = (unsigned short*)(ws + VSB_OFF);
    unsigned short* sig2b = (unsigned short*)(ws + SIG2B_OFF);
    unsigned short* chebb = (unsigned short*)(ws + CHEBB_OFF);
    unsigned short* expS  = (unsigned short*)(ws + EXPS_OFF);
    float* rhsc0  = ws + RHSC0_OFF;
    float* rhsc1  = ws + RHSC1_OFF;
    unsigned short* WtG   = (unsigned short*)(ws + WTG_OFF);
    float* partials = ws + PART_OFF;

    k_init<<<65, 256, 0, stream>>>(ws);
    k_cvtw<<<1, 256, 0, stream>>>(tcw, WtG);
    k_temporal<<<BB, 256, 0, stream>>>(x, U1, U2, U3, be, Ve, tat);
    k_xtat<<<(BB * NN_) / 256, 256, 0, stream>>>(x, tat, W1, W2, W3, lhsT, rhs2);
    k_cvt4<<<(NN_ * NN_) / 1024, 256, 0, stream>>>(Vs, Vsb);
    k_cvt4<<<(3 * NN_ * NN_) / 1024, 256, 0, stream>>>(cheb, chebb);
    k_sig2<<<(BB * NN_ * NN_) / 256, 256, 0, stream>>>(lhsT, rhs2, bs, (__hip_bfloat16*)sig2b);
    k_gemm_s_mfma<<<dim3(8, 8, BB), 256, 0, stream>>>((const short*)sig2b, (const short*)Vsb, expS, colsum);
    k_rhsc<<<dim3(16, BB, 2), 256, 0, stream>>>(chebb, expS, colsum, x, rhsc0);
    k_y7<<<(BB * NN_) / 16, 256, 0, stream>>>(rhsc0, rhsc1, WtG, Th, x, tcb, rcw, rcb, out, partials);
    k_fin2<<<1, 256, 0, stream>>>(partials, acc);
    k_norm<<<(BB * NN_ * 64 * TT) / 4 / 256, 256, 0, stream>>>(out, lng, lnb, acc);
}

// Round 8
// 437.049 us; speedup vs baseline: 1.2431x; 1.0157x over previous
//
#include <hip/hip_runtime.h>
#include <hip/hip_bf16.h>
#include <math.h>

#define BB 16
#define NN_ 1024
#define TT 12

typedef __attribute__((ext_vector_type(8))) short bf16x8;
typedef __attribute__((ext_vector_type(4))) float f32x4;

// ---------------- workspace layout (float units) ----------------
static const size_t ACC_OFF    = 0;          // 16
static const size_t COLSUM_OFF = 16;         // B*N = 16384
static const size_t TAT_OFF    = 16400;      // B*T*T = 2304
static const size_t LHST_OFF   = 18704;      // B*N*T = 196608
static const size_t RHS2_OFF   = 215312;     // B*T*N = 196608
static const size_t VSB_OFF    = 411920;     // N*N bf16 = 524288 floats
static const size_t SIG2B_OFF  = 936208;     // B*N*N bf16 = 8388608 floats
static const size_t CHEBB_OFF  = 9324816;    // 3*N*N bf16 = 1572864 floats
static const size_t EXPS_OFF   = 10897680;   // B*N*N bf16 = 8388608 floats
static const size_t RHSC0_OFF  = 19286288;   // B*K*N*F*T fp32 = 1769472
static const size_t RHSC1_OFF  = 21055760;   // B*K*N*F*T fp32 = 1769472
static const size_t WTG_OFF    = 22825232;   // 192*64 bf16 = 6144 floats
static const size_t PART_OFF   = 22831376;   // 2048 floats (block partial sums)
// total 22833424 floats = ~91 MB

__device__ __forceinline__ float wave_reduce_sum(float v) {
    #pragma unroll
    for (int off = 32; off > 0; off >>= 1) v += __shfl_down(v, off);
    return v;
}

__device__ __forceinline__ unsigned short f2b(float f) {
    __hip_bfloat16 h = __float2bfloat16(f);
    return *(unsigned short*)&h;
}
__device__ __forceinline__ float b2f(unsigned short u) {
    return __uint_as_float(((unsigned int)u) << 16);
}

// ---------------- init: zero acc + colsum ----------------
__global__ void k_init(float* __restrict__ ws) {
    int i = blockIdx.x * 256 + threadIdx.x;
    if (i < 16400) ws[i] = 0.f;
}

// ---------------- tcw -> WtG[d*64+c][cp] bf16 (one block) ----------------
__global__ __launch_bounds__(256) void k_cvtw(
    const float* __restrict__ tcw, unsigned short* __restrict__ WtG)
{
    for (int j = threadIdx.x; j < 12288; j += 256) {
        const int row = j >> 6;            // d*64 + c
        const int cp  = j & 63;
        const int d   = row >> 6;
        const int c   = row & 63;
        WtG[j] = f2b(tcw[c * 192 + 3 * cp + d]);
    }
}

// ---------------- temporal attention -> tat (B,T,T), 256 threads ----------------
__global__ __launch_bounds__(256) void k_temporal(
    const float* __restrict__ x, const float* __restrict__ U1,
    const float* __restrict__ U2, const float* __restrict__ U3,
    const float* __restrict__ be, const float* __restrict__ Ve,
    float* __restrict__ tat)
{
    const int b = blockIdx.x;
    const int tid = threadIdx.x;
    const int wid = tid >> 6, lane = tid & 63;
    float lA[36], lM[36];
    #pragma unroll
    for (int i = 0; i < 36; ++i) { lA[i] = 0.f; lM[i] = 0.f; }
    const float u30 = U3[0], u31 = U3[1], u32 = U3[2];
    for (int n = tid; n < NN_; n += 256) {
        const float* xp = x + ((size_t)b * NN_ + n) * 36;
        float xr[36];
        #pragma unroll
        for (int i = 0; i < 9; ++i) *(float4*)&xr[i*4] = *(const float4*)(xp + i*4);
        const float u1  = U1[n];
        const float u20 = U2[n], u21 = U2[NN_ + n], u22 = U2[2*NN_ + n];
        #pragma unroll
        for (int t = 0; t < 12; ++t) {
            float ru = xr[t]*u30 + xr[12+t]*u31 + xr[24+t]*u32;
            lM[t]    += u20 * ru;
            lM[12+t] += u21 * ru;
            lM[24+t] += u22 * ru;
            lA[t]    += xr[t]    * u1;
            lA[12+t] += xr[12+t] * u1;
            lA[24+t] += xr[24+t] * u1;
        }
    }
    __shared__ float pA[4][36], pM[4][36];
    __shared__ float tA[36], tM[36], sgs[144], es[144], cmax[12], csum[12];
    #pragma unroll
    for (int i = 0; i < 36; ++i) {
        float v = wave_reduce_sum(lA[i]);
        if (lane == 0) pA[wid][i] = v;
        float w = wave_reduce_sum(lM[i]);
        if (lane == 0) pM[wid][i] = w;
    }
    __syncthreads();
    if (tid < 36) tA[tid] = pA[0][tid] + pA[1][tid] + pA[2][tid] + pA[3][tid];
    else if (tid < 72) {
        int i = tid - 36;
        tM[i] = pM[0][i] + pM[1][i] + pM[2][i] + pM[3][i];
    }
    __syncthreads();
    if (tid < 144) {
        int t = tid / 12, u = tid % 12;
        float p = tA[t]*tM[u] + tA[12+t]*tM[12+u] + tA[24+t]*tM[24+u];
        p += be[tid];
        sgs[tid] = 1.f / (1.f + expf(-p));
    }
    __syncthreads();
    if (tid < 144) {
        int i = tid / 12, j = tid % 12;
        float e = 0.f;
        #pragma unroll
        for (int k = 0; k < 12; ++k) e += sgs[i*12 + k] * Ve[j*12 + k];
        es[tid] = e;
    }
    __syncthreads();
    if (tid < 12) {
        int j = tid;
        float m = -1e30f;
        for (int i = 0; i < 12; ++i) m = fmaxf(m, es[i*12 + j]);
        float sx = 0.f;
        for (int i = 0; i < 12; ++i) sx += expf(es[i*12 + j] - m);
        cmax[j] = m; csum[j] = sx;
    }
    __syncthreads();
    if (tid < 144) {
        int j = tid % 12;
        tat[(size_t)b*144 + tid] = expf(es[tid] - cmax[j]) / csum[j];
    }
}

// ---------------- x_tat projections -> lhsT (B,N,T), rhs2 (B,T,N) ----------------
__global__ __launch_bounds__(256) void k_xtat(
    const float* __restrict__ x, const float* __restrict__ tat,
    const float* __restrict__ W1, const float* __restrict__ W2,
    const float* __restrict__ W3,
    float* __restrict__ lhsT, float* __restrict__ rhs2)
{
    const int id = blockIdx.x * 256 + threadIdx.x;
    const int b = id >> 10, n = id & 1023;
    const float* xp = x + (size_t)id * 36;
    float xr[36];
    #pragma unroll
    for (int i = 0; i < 9; ++i) *(float4*)&xr[i*4] = *(const float4*)(xp + i*4);
    const float* tp = tat + (size_t)b * 144;
    float xt[36];
    #pragma unroll
    for (int f = 0; f < 3; ++f)
        #pragma unroll
        for (int u = 0; u < 12; ++u) {
            float s = 0.f;
            #pragma unroll
            for (int t = 0; t < 12; ++t) s += xr[f*12 + t] * tp[t*12 + u];
            xt[f*12 + u] = s;
        }
    float lA0 = 0.f, lA1 = 0.f, lA2 = 0.f;
    #pragma unroll
    for (int t = 0; t < 12; ++t) {
        float w = W1[t];
        lA0 += xt[t]*w; lA1 += xt[12+t]*w; lA2 += xt[24+t]*w;
    }
    #pragma unroll
    for (int t2 = 0; t2 < 12; ++t2)
        lhsT[(size_t)id*12 + t2] = lA0*W2[t2] + lA1*W2[12+t2] + lA2*W2[24+t2];
    const float w30 = W3[0], w31 = W3[1], w32 = W3[2];
    #pragma unroll
    for (int u = 0; u < 12; ++u)
        rhs2[((size_t)b*12 + u)*NN_ + n] = xt[u]*w30 + xt[12+u]*w31 + xt[24+u]*w32;
}

// ---------------- sig2 (B,N,N) -> bf16 ----------------
__global__ __launch_bounds__(256) void k_sig2(
    const float* __restrict__ lhsT, const float* __restrict__ rhs2,
    const float* __restrict__ bs, __hip_bfloat16* __restrict__ sig2b)
{
    const unsigned int idx = blockIdx.x * 256u + threadIdx.x;
    const int m = (int)(idx & 1023u);
    const unsigned int bn = idx >> 10;
    const int b = (int)(bn >> 10);
    const int n = (int)(bn & 1023u);
    const float* lp = lhsT + (size_t)bn * 12;
    const float* rp = rhs2 + (size_t)b * 12 * NN_ + m;
    float z = bs[(size_t)n * NN_ + m];
    #pragma unroll
    for (int t = 0; t < 12; ++t) z += lp[t] * rp[(size_t)t * NN_];
    sig2b[idx] = __float2bfloat16(1.f / (1.f + expf(-z)));
}

// ---------------- fp32 -> bf16 converters ----------------
__global__ __launch_bounds__(256) void k_cvt4(
    const float* __restrict__ src, unsigned short* __restrict__ dst)
{
    const int i = blockIdx.x * 256 + threadIdx.x;
    float4 v = ((const float4*)src)[i];
    ushort4 o;
    o.x = f2b(v.x); o.y = f2b(v.y); o.z = f2b(v.z); o.w = f2b(v.w);
    ((ushort4*)dst)[i] = o;
}

// ---------------- S = sig2 @ Vs^T, fused exp + colsum; store expS bf16 ----------------
__global__ __launch_bounds__(256) void k_gemm_s_mfma(
    const short* __restrict__ A,   // sig2b [B][1024][1024] bf16
    const short* __restrict__ Bm,  // Vsb   [1024][1024] bf16
    unsigned short* __restrict__ E, // expS bf16 out
    float* __restrict__ colsum)
{
    __shared__ short As[128 * 32];
    __shared__ short Bs[128 * 32];
    const int b  = blockIdx.z;
    const int i0 = blockIdx.y * 128;
    const int j0 = blockIdx.x * 128;
    const int tid = threadIdx.x;
    const int wid = tid >> 6;
    const int lane = tid & 63;
    const int wr = wid & 1, wc = wid >> 1;
    const short* Ab = A + (size_t)b * NN_ * NN_;

    f32x4 acc[4][4];
    const f32x4 z4 = {0.f, 0.f, 0.f, 0.f};
    #pragma unroll
    for (int m = 0; m < 4; ++m)
        #pragma unroll
        for (int n = 0; n < 4; ++n) acc[m][n] = z4;

    const int srow = lane >> 2;
    const int schk = lane & 3;
    const int fr = lane & 15;
    const int kb = (lane >> 4) * 8;

    for (int k0 = 0; k0 < NN_; k0 += 32) {
        #pragma unroll
        for (int q = 0; q < 2; ++q) {
            const int rb = (wid * 2 + q) * 16;
            const short* srcA = Ab + (size_t)(i0 + rb + srow) * NN_ + k0 + schk * 8;
            const short* srcB = Bm + (size_t)(j0 + rb + srow) * NN_ + k0 + schk * 8;
            __builtin_amdgcn_global_load_lds(
                (const __attribute__((address_space(1))) unsigned int*)srcA,
                (__attribute__((address_space(3))) unsigned int*)(As + rb * 32), 16, 0, 0);
            __builtin_amdgcn_global_load_lds(
                (const __attribute__((address_space(1))) unsigned int*)srcB,
                (__attribute__((address_space(3))) unsigned int*)(Bs + rb * 32), 16, 0, 0);
        }
        __syncthreads();
        bf16x8 aF[4], bF[4];
        #pragma unroll
        for (int m = 0; m < 4; ++m)
            aF[m] = *(const bf16x8*)(As + (wr*64 + m*16 + fr) * 32 + kb);
        #pragma unroll
        for (int n = 0; n < 4; ++n)
            bF[n] = *(const bf16x8*)(Bs + (wc*64 + n*16 + fr) * 32 + kb);
        #pragma unroll
        for (int m = 0; m < 4; ++m)
            #pragma unroll
            for (int n = 0; n < 4; ++n)
                acc[m][n] = __builtin_amdgcn_mfma_f32_16x16x32_bf16(aF[m], bF[n], acc[m][n], 0, 0, 0);
        __syncthreads();
    }
    unsigned short* Ep = E + (size_t)b * NN_ * NN_;
    const int cn = lane & 15;
    const int r0 = (lane >> 4) * 4;
    float cs[4] = {0.f, 0.f, 0.f, 0.f};
    #pragma unroll
    for (int m = 0; m < 4; ++m)
        #pragma unroll
        for (int n = 0; n < 4; ++n)
            #pragma unroll
            for (int r = 0; r < 4; ++r) {
                float e = __expf(acc[m][n][r]);
                Ep[(size_t)(i0 + wr*64 + m*16 + r0 + r) * NN_ + j0 + wc*64 + n*16 + cn] = f2b(e);
                cs[n] += e;
            }
    #pragma unroll
    for (int n = 0; n < 4; ++n) {
        float s = cs[n];
        s += __shfl_xor(s, 16);
        s += __shfl_xor(s, 32);
        if (lane < 16)
            atomicAdd(&colsum[b * NN_ + j0 + wc*64 + n*16 + cn], s);
    }
}

// ---- rhs_c: LDS-vectorized. Block (m-tile 64, b, z-half). Wave = n-subrange.
// Thread tile: 4 m x 9 j, acc[k3][mi4][jj9]. w pre-multiplied (cheb*sat/colsum).
#define XSS 48
__global__ __launch_bounds__(256) void k_rhsc(
    const unsigned short* __restrict__ chebb, const unsigned short* __restrict__ expS,
    const float* __restrict__ colsum, const float* __restrict__ x,
    float* __restrict__ rhsc)
{
    __shared__ float w[3 * 16 * 64];      // 12 KB, w[k][u][m]
    __shared__ float xs[16 * XSS];        // 3 KB, xs[u][sec*12+off]
    __shared__ float red[256 * 9];        // 9 KB reduction scratch
    const int m0 = blockIdx.x * 64;
    const int b  = blockIdx.y;
    const int z  = blockIdx.z;
    const int nbase = z * 512;
    const int tid = threadIdx.x;
    const int usplit = tid >> 6;          // wave id: n-offset within chunk
    const int lane = tid & 63;
    const int mg = lane >> 2;             // m-group (4 m)
    const int q  = lane & 3;              // j-section (9 j)

    // staging roles
    const int nn  = tid >> 4;             // 0..15
    const int mm  = (tid & 15) << 2;      // 0,4,..60
    float rcs[4];
    {
        const float* cp = colsum + b * NN_ + m0 + mm;
        rcs[0] = 1.f / cp[0]; rcs[1] = 1.f / cp[1];
        rcs[2] = 1.f / cp[2]; rcs[3] = 1.f / cp[3];
    }

    float acc[3][4][9];
    #pragma unroll
    for (int k = 0; k < 3; ++k)
        #pragma unroll
        for (int mi = 0; mi < 4; ++mi)
            #pragma unroll
            for (int jj = 0; jj < 9; ++jj) acc[k][mi][jj] = 0.f;

    const unsigned short* sb = expS + (size_t)b * NN_ * NN_;
    const float* xb = x + (size_t)b * NN_ * 36;

    for (int n0 = nbase; n0 < nbase + 512; n0 += 16) {
        // ---- stage w[k][nn][mm..+3] = cheb*sat*rcs ----
        {
            ushort4 s4 = *(const ushort4*)(sb + (size_t)(n0 + nn) * NN_ + m0 + mm);
            float st0 = b2f(s4.x) * rcs[0], st1 = b2f(s4.y) * rcs[1];
            float st2 = b2f(s4.z) * rcs[2], st3 = b2f(s4.w) * rcs[3];
            #pragma unroll
            for (int k = 0; k < 3; ++k) {
                ushort4 c4 = *(const ushort4*)(chebb + (size_t)k * NN_ * NN_ + (size_t)(n0 + nn) * NN_ + m0 + mm);
                float4 wv;
                wv.x = b2f(c4.x) * st0; wv.y = b2f(c4.y) * st1;
                wv.z = b2f(c4.z) * st2; wv.w = b2f(c4.w) * st3;
                *(float4*)&w[(k * 16 + nn) * 64 + mm] = wv;
            }
        }
        // ---- stage xs (9->12 padded sections) ----
        for (int idx = tid; idx < 576; idx += 256) {
            const int n2 = idx / 36;
            const int j = idx - n2 * 36;
            const int sec = j / 9;
            const int off = j - sec * 9;
            xs[n2 * XSS + sec * 12 + off] = xb[(size_t)(n0 + n2) * 36 + j];
        }
        __syncthreads();
        // ---- compute: wave handles u = usplit*4 .. +3 (wave-uniform u) ----
        #pragma unroll
        for (int ui = 0; ui < 4; ++ui) {
            const int u = usplit * 4 + ui;
            float xv[9];
            *(float4*)&xv[0] = *(const float4*)&xs[u * XSS + q * 12];
            *(float4*)&xv[4] = *(const float4*)&xs[u * XSS + q * 12 + 4];
            xv[8] = xs[u * XSS + q * 12 + 8];
            float wv[3][4];
            #pragma unroll
            for (int k = 0; k < 3; ++k)
                *(float4*)&wv[k][0] = *(const float4*)&w[(k * 16 + u) * 64 + mg * 4];
            #pragma unroll
            for (int k = 0; k < 3; ++k)
                #pragma unroll
                for (int mi = 0; mi < 4; ++mi) {
                    const float wk = wv[k][mi];
                    #pragma unroll
                    for (int jj = 0; jj < 9; ++jj)
                        acc[k][mi][jj] += wk * xv[jj];
                }
        }
        __syncthreads();
    }

    // ---- cross-wave reduction + store: 12 rounds (k, mi) ----
    float* outb = rhsc + (size_t)z * 1769472;
    #pragma unroll
    for (int r = 0; r < 12; ++r) {
        const int k = r >> 2, mi = r & 3;
        #pragma unroll
        for (int jj = 0; jj < 9; ++jj) red[tid * 9 + jj] = acc[k][mi][jj];
        __syncthreads();
        if (usplit == 0) {
            float s[9];
            #pragma unroll
            for (int jj = 0; jj < 9; ++jj)
                s[jj] = red[lane * 9 + jj] + red[(64 + lane) * 9 + jj]
                      + red[(128 + lane) * 9 + jj] + red[(192 + lane) * 9 + jj];
            float* rp = outb + (((size_t)b * 3 + k) * NN_ + m0 + mg * 4 + mi) * 36 + q * 9;
            #pragma unroll
            for (int jj = 0; jj < 9; ++jj) rp[jj] = s[jj];
        }
        __syncthreads();
    }
}

// ---- fused gcn + tconv (3 shifted GEMMs, transposed: out[c][nt]) + residual + relu ----
#define G2S 72            // Gs2 row stride (halfwords): 64 + 8 pad
#define RSTR 112          // Rs item stride (floats): 108 + 4 pad
__global__ __launch_bounds__(256) void k_y7(
    const float* __restrict__ rhsc0, const float* __restrict__ rhsc1,
    const unsigned short* __restrict__ WtG,
    const float* __restrict__ Theta, const float* __restrict__ x,
    const float* __restrict__ tcb,
    const float* __restrict__ rcw, const float* __restrict__ rcb,
    float* __restrict__ y, float* __restrict__ partials)
{
    __shared__ unsigned short Gs2[193 * G2S];   // 27.8 KB (row 192 = zeros)
    __shared__ float Rs[16 * RSTR];             // 7.2 KB
    __shared__ float xls[16 * 36];              // 2.25 KB
    __shared__ float red[8];
    const int tid = threadIdx.x;
    const int wid = tid >> 6, lane = tid & 63;
    const int blk = blockIdx.x;                 // items blk*16 .. +15

    // ---- stage Rs = rhsc0 + rhsc1, coalesced float4 ----
    const int bb = (blk * 16) >> 10;
    const int nb = (blk * 16) & 1023;
    for (int idx = tid; idx < 432; idx += 256) {
        const int i = idx / 27;
        const int r = idx - i * 27;
        const int k = r / 9;
        const int q = r - k * 9;
        const size_t off = (((size_t)bb * 3 + k) * NN_ + nb + i) * 36 + q * 4;
        float4 a = *(const float4*)(rhsc0 + off);
        float4 b = *(const float4*)(rhsc1 + off);
        a.x += b.x; a.y += b.y; a.z += b.z; a.w += b.w;
        *(float4*)&Rs[i * RSTR + k * 36 + q * 4] = a;
    }
    if (tid < 36) ((unsigned int*)(Gs2 + 192 * G2S))[tid] = 0u;
    if (tid < 144)
        ((float4*)xls)[tid] = ((const float4*)(x + (size_t)blk * 16 * 36))[tid];
    __syncthreads();

    // ---- phase 1: gcn -> Gs2[nt][cp]. wave wid: items 4*wid..+3, lane = cp ----
    {
        float th[9];
        #pragma unroll
        for (int j = 0; j < 9; ++j) th[j] = Theta[j * 64 + lane];
        #pragma unroll
        for (int ii = 0; ii < 4; ++ii) {
            const int i = wid * 4 + ii;
            float g[12];
            #pragma unroll
            for (int t = 0; t < 12; ++t) g[t] = 0.f;
            #pragma unroll
            for (int kf = 0; kf < 9; ++kf) {
                const float* rp = Rs + i * RSTR + kf * 12;
                float4 v0 = *(const float4*)(rp);
                float4 v1 = *(const float4*)(rp + 4);
                float4 v2 = *(const float4*)(rp + 8);
                const float w = th[kf];
                g[0] += v0.x*w; g[1] += v0.y*w; g[2]  += v0.z*w; g[3]  += v0.w*w;
                g[4] += v1.x*w; g[5] += v1.y*w; g[6]  += v1.z*w; g[7]  += v1.w*w;
                g[8] += v2.x*w; g[9] += v2.y*w; g[10] += v2.z*w; g[11] += v2.w*w;
            }
            #pragma unroll
            for (int t = 0; t < 12; ++t)
                Gs2[(i*12 + t) * G2S + lane] = f2b(fmaxf(g[t], 0.f));
        }
    }
    __syncthreads();

    // ---- phase 2: out[c][nt], A = W (m=c), B = G (n=nt). Coalesced stores. ----
    const int cl = lane & 15, kg = lane >> 4;
    bf16x8 aW[3][2];
    #pragma unroll
    for (int d = 0; d < 3; ++d)
        #pragma unroll
        for (int kb = 0; kb < 2; ++kb)
            aW[d][kb] = *(const bf16x8*)(WtG + (d*64 + wid*16 + cl) * 64 + kb*32 + kg*8);
    float tb[4], rb[4], rw0[4], rw1[4], rw2[4];
    #pragma unroll
    for (int r = 0; r < 4; ++r) {
        const int c = wid*16 + kg*4 + r;
        tb[r] = tcb[c]; rb[r] = rcb[c];
        rw0[r] = rcw[c*3]; rw1[r] = rcw[c*3+1]; rw2[r] = rcw[c*3+2];
    }
    float ls = 0.f, lss = 0.f;
    #pragma unroll
    for (int ct = 0; ct < 12; ++ct) {
        const int nt = ct * 16 + cl;
        const int i = nt / 12;
        const int t = nt - i * 12;
        const unsigned short* g1 = Gs2 + nt * G2S + kg * 8;
        const unsigned short* g0 = (t == 0)  ? (Gs2 + 192 * G2S + kg * 8) : (g1 - G2S);
        const unsigned short* g2 = (t == 11) ? (Gs2 + 192 * G2S + kg * 8) : (g1 + G2S);
        f32x4 a4 = {0.f, 0.f, 0.f, 0.f};
        #pragma unroll
        for (int kb = 0; kb < 2; ++kb) {
            a4 = __builtin_amdgcn_mfma_f32_16x16x32_bf16(aW[0][kb], *(const bf16x8*)(g0 + kb*32), a4, 0, 0, 0);
            a4 = __builtin_amdgcn_mfma_f32_16x16x32_bf16(aW[1][kb], *(const bf16x8*)(g1 + kb*32), a4, 0, 0, 0);
            a4 = __builtin_amdgcn_mfma_f32_16x16x32_bf16(aW[2][kb], *(const bf16x8*)(g2 + kb*32), a4, 0, 0, 0);
        }
        const float x0 = xls[i*36 + t];
        const float x1 = xls[i*36 + 12 + t];
        const float x2 = xls[i*36 + 24 + t];
        float* yp = y + (size_t)(blk*16 + i) * 768 + (wid*16 + kg*4) * 12 + t;
        #pragma unroll
        for (int r = 0; r < 4; ++r) {
            const float xres = rb[r] + x0*rw0[r] + x1*rw1[r] + x2*rw2[r];
            const float v = fmaxf(xres + a4[r] + tb[r], 0.f);
            ls += v; lss += v * v;
            yp[r * 12] = v;
        }
    }
    ls  = wave_reduce_sum(ls);
    lss = wave_reduce_sum(lss);
    if (lane == 0) { red[wid] = ls; red[4 + wid] = lss; }
    __syncthreads();
    if (tid == 0) {
        partials[blk]        = red[0] + red[1] + red[2] + red[3];
        partials[1024 + blk] = red[4] + red[5] + red[6] + red[7];
    }
}

// ---------------- reduce partials -> mean / inv_std ----------------
__global__ __launch_bounds__(256) void k_fin2(
    const float* __restrict__ partials, float* __restrict__ acc)
{
    const int tid = threadIdx.x;
    const int wid = tid >> 6, lane = tid & 63;
    float s = 0.f, ss = 0.f;
    #pragma unroll
    for (int j = tid; j < 1024; j += 256) {
        s  += partials[j];
        ss += partials[1024 + j];
    }
    s  = wave_reduce_sum(s);
    ss = wave_reduce_sum(ss);
    __shared__ float rs[4], rss[4];
    if (lane == 0) { rs[wid] = s; rss[wid] = ss; }
    __syncthreads();
    if (tid == 0) {
        const float cnt = (float)((size_t)BB * NN_ * 64 * TT);
        float tot  = rs[0] + rs[1] + rs[2] + rs[3];
        float tots = rss[0] + rss[1] + rss[2] + rss[3];
        float mu = tot / cnt;
        float var = tots / cnt - mu * mu;
        acc[2] = mu;
        acc[3] = rsqrtf(var + 1e-5f);
    }
}

// ---------------- normalize in place on d_out ----------------
__global__ __launch_bounds__(256) void k_norm(
    float* __restrict__ y, const float* __restrict__ lng,
    const float* __restrict__ lnb, const float* __restrict__ acc)
{
    const unsigned int i = blockIdx.x * 256u + threadIdx.x;
    const float mu = acc[2], inv = acc[3];
    float4 v  = ((const float4*)y)[i];
    float4 gv = ((const float4*)lng)[i];
    float4 bv = ((const float4*)lnb)[i];
    v.x = (v.x - mu) * inv * gv.x + bv.x;
    v.y = (v.y - mu) * inv * gv.y + bv.y;
    v.z = (v.z - mu) * inv * gv.z + bv.z;
    v.w = (v.w - mu) * inv * gv.w + bv.w;
    ((float4*)y)[i] = v;
}

extern "C" void kernel_launch(void* const* d_in, const int* in_sizes, int n_in,
                              void* d_out, int out_size, void* d_ws, size_t ws_size,
                              hipStream_t stream)
{
    const float* x    = (const float*)d_in[0];
    const float* U1   = (const float*)d_in[1];
    const float* U2   = (const float*)d_in[2];
    const float* U3   = (const float*)d_in[3];
    const float* be   = (const float*)d_in[4];
    const float* Ve   = (const float*)d_in[5];
    const float* W1   = (const float*)d_in[6];
    const float* W2   = (const float*)d_in[7];
    const float* W3   = (const float*)d_in[8];
    const float* bs   = (const float*)d_in[9];
    const float* Vs   = (const float*)d_in[10];
    const float* cheb = (const float*)d_in[11];
    const float* Th   = (const float*)d_in[12];
    const float* tcw  = (const float*)d_in[13];
    const float* tcb  = (const float*)d_in[14];
    const float* rcw  = (const float*)d_in[15];
    const float* rcb  = (const float*)d_in[16];
    const float* lng  = (const float*)d_in[17];
    const float* lnb  = (const float*)d_in[18];
    float* out = (float*)d_out;
    float* ws  = (float*)d_ws;

    float* acc    = ws + ACC_OFF;
    float* colsum = ws + COLSUM_OFF;
    float* tat    = ws + TAT_OFF;
    float* lhsT   = ws + LHST_OFF;
    float* rhs2   = ws + RHS2_OFF;
    unsigned short* Vsb   = (unsigned short*)(ws + VSB_OFF);
    unsigned short* sig2b = (unsigned short*)(ws + SIG2B_OFF);
    unsigned short* chebb = (unsigned short*)(ws + CHEBB_OFF);
    unsigned short* expS  = (unsigned short*)(ws + EXPS_OFF);
    float* rhsc0  = ws + RHSC0_OFF;
    float* rhsc1  = ws + RHSC1_OFF;
    unsigned short* WtG   = (unsigned short*)(ws + WTG_OFF);
    float* partials = ws + PART_OFF;

    k_init<<<65, 256, 0, stream>>>(ws);
    k_cvtw<<<1, 256, 0, stream>>>(tcw, WtG);
    k_temporal<<<BB, 256, 0, stream>>>(x, U1, U2, U3, be, Ve, tat);
    k_xtat<<<(BB * NN_) / 256, 256, 0, stream>>>(x, tat, W1, W2, W3, lhsT, rhs2);
    k_cvt4<<<(NN_ * NN_) / 1024, 256, 0, stream>>>(Vs, Vsb);
    k_cvt4<<<(3 * NN_ * NN_) / 1024, 256, 0, stream>>>(cheb, chebb);
    k_sig2<<<(BB * NN_ * NN_) / 256, 256, 0, stream>>>(lhsT, rhs2, bs, (__hip_bfloat16*)sig2b);
    k_gemm_s_mfma<<<dim3(8, 8, BB), 256, 0, stream>>>((const short*)sig2b, (const short*)Vsb, expS, colsum);
    k_rhsc<<<dim3(16, BB, 2), 256, 0, stream>>>(chebb, expS, colsum, x, rhsc0);
    k_y7<<<(BB * NN_) / 16, 256, 0, stream>>>(rhsc0, rhsc1, WtG, Th, x, tcb, rcw, rcb, out, partials);
    k_fin2<<<1, 256, 0, stream>>>(partials, acc);
    k_norm<<<(BB * NN_ * 64 * TT) / 4 / 256, 256, 0, stream>>>(out, lng, lnb, acc);
}

// Round 9
// 414.270 us; speedup vs baseline: 1.3114x; 1.0550x over previous
//
#include <hip/hip_runtime.h>
#include <hip/hip_bf16.h>
#include <math.h>

#define BB 16
#define NN_ 1024
#define TT 12

typedef __attribute__((ext_vector_type(8))) short bf16x8;
typedef __attribute__((ext_vector_type(4))) float f32x4;

// ---------------- workspace layout (float units) ----------------
static const size_t ACC_OFF    = 0;          // 16
static const size_t COLSUM_OFF = 16;         // B*N = 16384
static const size_t TAT_OFF    = 16400;      // B*T*T = 2304
static const size_t LHST_OFF   = 18704;      // B*N*T = 196608
static const size_t RHS2_OFF   = 215312;     // B*T*N = 196608
static const size_t VSB_OFF    = 411920;     // N*N bf16 = 524288 floats
static const size_t SIG2B_OFF  = 936208;     // B*N*N bf16 = 8388608 floats
static const size_t CHEBB_OFF  = 9324816;    // 3*N*N bf16 = 1572864 floats
static const size_t EXPS_OFF   = 10897680;   // B*N*N bf16 = 8388608 floats
static const size_t RHSC_OFF   = 19286288;   // 4 x B*K*N*F*T fp32 = 4*1769472
static const size_t WTG_OFF    = 26364176;   // 192*64 bf16 = 6144 floats
static const size_t PART_OFF   = 26370320;   // 2048 floats
// total ~26372368 floats = ~105 MB

#define RHSC_SZ 1769472

__device__ __forceinline__ float wave_reduce_sum(float v) {
    #pragma unroll
    for (int off = 32; off > 0; off >>= 1) v += __shfl_down(v, off);
    return v;
}

__device__ __forceinline__ unsigned short f2b(float f) {
    __hip_bfloat16 h = __float2bfloat16(f);
    return *(unsigned short*)&h;
}
__device__ __forceinline__ float b2f(unsigned short u) {
    return __uint_as_float(((unsigned int)u) << 16);
}

// ---------------- init: zero acc + colsum ----------------
__global__ void k_init(float* __restrict__ ws) {
    int i = blockIdx.x * 256 + threadIdx.x;
    if (i < 16400) ws[i] = 0.f;
}

// ---------------- tcw -> WtG[d*64+c][cp] bf16 (one block) ----------------
__global__ __launch_bounds__(256) void k_cvtw(
    const float* __restrict__ tcw, unsigned short* __restrict__ WtG)
{
    for (int j = threadIdx.x; j < 12288; j += 256) {
        const int row = j >> 6;
        const int cp  = j & 63;
        const int d   = row >> 6;
        const int c   = row & 63;
        WtG[j] = f2b(tcw[c * 192 + 3 * cp + d]);
    }
}

// ---------------- temporal attention -> tat (B,T,T), 256 threads ----------------
__global__ __launch_bounds__(256) void k_temporal(
    const float* __restrict__ x, const float* __restrict__ U1,
    const float* __restrict__ U2, const float* __restrict__ U3,
    const float* __restrict__ be, const float* __restrict__ Ve,
    float* __restrict__ tat)
{
    const int b = blockIdx.x;
    const int tid = threadIdx.x;
    const int wid = tid >> 6, lane = tid & 63;
    float lA[36], lM[36];
    #pragma unroll
    for (int i = 0; i < 36; ++i) { lA[i] = 0.f; lM[i] = 0.f; }
    const float u30 = U3[0], u31 = U3[1], u32 = U3[2];
    for (int n = tid; n < NN_; n += 256) {
        const float* xp = x + ((size_t)b * NN_ + n) * 36;
        float xr[36];
        #pragma unroll
        for (int i = 0; i < 9; ++i) *(float4*)&xr[i*4] = *(const float4*)(xp + i*4);
        const float u1  = U1[n];
        const float u20 = U2[n], u21 = U2[NN_ + n], u22 = U2[2*NN_ + n];
        #pragma unroll
        for (int t = 0; t < 12; ++t) {
            float ru = xr[t]*u30 + xr[12+t]*u31 + xr[24+t]*u32;
            lM[t]    += u20 * ru;
            lM[12+t] += u21 * ru;
            lM[24+t] += u22 * ru;
            lA[t]    += xr[t]    * u1;
            lA[12+t] += xr[12+t] * u1;
            lA[24+t] += xr[24+t] * u1;
        }
    }
    __shared__ float pA[4][36], pM[4][36];
    __shared__ float tA[36], tM[36], sgs[144], es[144], cmax[12], csum[12];
    #pragma unroll
    for (int i = 0; i < 36; ++i) {
        float v = wave_reduce_sum(lA[i]);
        if (lane == 0) pA[wid][i] = v;
        float w = wave_reduce_sum(lM[i]);
        if (lane == 0) pM[wid][i] = w;
    }
    __syncthreads();
    if (tid < 36) tA[tid] = pA[0][tid] + pA[1][tid] + pA[2][tid] + pA[3][tid];
    else if (tid < 72) {
        int i = tid - 36;
        tM[i] = pM[0][i] + pM[1][i] + pM[2][i] + pM[3][i];
    }
    __syncthreads();
    if (tid < 144) {
        int t = tid / 12, u = tid % 12;
        float p = tA[t]*tM[u] + tA[12+t]*tM[12+u] + tA[24+t]*tM[24+u];
        p += be[tid];
        sgs[tid] = 1.f / (1.f + expf(-p));
    }
    __syncthreads();
    if (tid < 144) {
        int i = tid / 12, j = tid % 12;
        float e = 0.f;
        #pragma unroll
        for (int k = 0; k < 12; ++k) e += sgs[i*12 + k] * Ve[j*12 + k];
        es[tid] = e;
    }
    __syncthreads();
    if (tid < 12) {
        int j = tid;
        float m = -1e30f;
        for (int i = 0; i < 12; ++i) m = fmaxf(m, es[i*12 + j]);
        float sx = 0.f;
        for (int i = 0; i < 12; ++i) sx += expf(es[i*12 + j] - m);
        cmax[j] = m; csum[j] = sx;
    }
    __syncthreads();
    if (tid < 144) {
        int j = tid % 12;
        tat[(size_t)b*144 + tid] = expf(es[tid] - cmax[j]) / csum[j];
    }
}

// ---------------- x_tat projections -> lhsT (B,N,T), rhs2 (B,T,N) ----------------
__global__ __launch_bounds__(256) void k_xtat(
    const float* __restrict__ x, const float* __restrict__ tat,
    const float* __restrict__ W1, const float* __restrict__ W2,
    const float* __restrict__ W3,
    float* __restrict__ lhsT, float* __restrict__ rhs2)
{
    const int id = blockIdx.x * 256 + threadIdx.x;
    const int b = id >> 10, n = id & 1023;
    const float* xp = x + (size_t)id * 36;
    float xr[36];
    #pragma unroll
    for (int i = 0; i < 9; ++i) *(float4*)&xr[i*4] = *(const float4*)(xp + i*4);
    const float* tp = tat + (size_t)b * 144;
    float xt[36];
    #pragma unroll
    for (int f = 0; f < 3; ++f)
        #pragma unroll
        for (int u = 0; u < 12; ++u) {
            float s = 0.f;
            #pragma unroll
            for (int t = 0; t < 12; ++t) s += xr[f*12 + t] * tp[t*12 + u];
            xt[f*12 + u] = s;
        }
    float lA0 = 0.f, lA1 = 0.f, lA2 = 0.f;
    #pragma unroll
    for (int t = 0; t < 12; ++t) {
        float w = W1[t];
        lA0 += xt[t]*w; lA1 += xt[12+t]*w; lA2 += xt[24+t]*w;
    }
    #pragma unroll
    for (int t2 = 0; t2 < 12; ++t2)
        lhsT[(size_t)id*12 + t2] = lA0*W2[t2] + lA1*W2[12+t2] + lA2*W2[24+t2];
    const float w30 = W3[0], w31 = W3[1], w32 = W3[2];
    #pragma unroll
    for (int u = 0; u < 12; ++u)
        rhs2[((size_t)b*12 + u)*NN_ + n] = xt[u]*w30 + xt[12+u]*w31 + xt[24+u]*w32;
}

// ---------------- sig2 (B,N,N) -> bf16 ----------------
__global__ __launch_bounds__(256) void k_sig2(
    const float* __restrict__ lhsT, const float* __restrict__ rhs2,
    const float* __restrict__ bs, __hip_bfloat16* __restrict__ sig2b)
{
    const unsigned int idx = blockIdx.x * 256u + threadIdx.x;
    const int m = (int)(idx & 1023u);
    const unsigned int bn = idx >> 10;
    const int b = (int)(bn >> 10);
    const int n = (int)(bn & 1023u);
    const float* lp = lhsT + (size_t)bn * 12;
    const float* rp = rhs2 + (size_t)b * 12 * NN_ + m;
    float z = bs[(size_t)n * NN_ + m];
    #pragma unroll
    for (int t = 0; t < 12; ++t) z += lp[t] * rp[(size_t)t * NN_];
    sig2b[idx] = __float2bfloat16(1.f / (1.f + expf(-z)));
}

// ---------------- fp32 -> bf16 converters ----------------
__global__ __launch_bounds__(256) void k_cvt4(
    const float* __restrict__ src, unsigned short* __restrict__ dst)
{
    const int i = blockIdx.x * 256 + threadIdx.x;
    float4 v = ((const float4*)src)[i];
    ushort4 o;
    o.x = f2b(v.x); o.y = f2b(v.y); o.z = f2b(v.z); o.w = f2b(v.w);
    ((ushort4*)dst)[i] = o;
}

// ---------------- S = sig2 @ Vs^T, fused exp + colsum; store expS bf16 ----------------
__global__ __launch_bounds__(256) void k_gemm_s_mfma(
    const short* __restrict__ A, const short* __restrict__ Bm,
    unsigned short* __restrict__ E, float* __restrict__ colsum)
{
    __shared__ short As[128 * 32];
    __shared__ short Bs[128 * 32];
    const int b  = blockIdx.z;
    const int i0 = blockIdx.y * 128;
    const int j0 = blockIdx.x * 128;
    const int tid = threadIdx.x;
    const int wid = tid >> 6;
    const int lane = tid & 63;
    const int wr = wid & 1, wc = wid >> 1;
    const short* Ab = A + (size_t)b * NN_ * NN_;

    f32x4 acc[4][4];
    const f32x4 z4 = {0.f, 0.f, 0.f, 0.f};
    #pragma unroll
    for (int m = 0; m < 4; ++m)
        #pragma unroll
        for (int n = 0; n < 4; ++n) acc[m][n] = z4;

    const int srow = lane >> 2;
    const int schk = lane & 3;
    const int fr = lane & 15;
    const int kb = (lane >> 4) * 8;

    for (int k0 = 0; k0 < NN_; k0 += 32) {
        #pragma unroll
        for (int q = 0; q < 2; ++q) {
            const int rb = (wid * 2 + q) * 16;
            const short* srcA = Ab + (size_t)(i0 + rb + srow) * NN_ + k0 + schk * 8;
            const short* srcB = Bm + (size_t)(j0 + rb + srow) * NN_ + k0 + schk * 8;
            __builtin_amdgcn_global_load_lds(
                (const __attribute__((address_space(1))) unsigned int*)srcA,
                (__attribute__((address_space(3))) unsigned int*)(As + rb * 32), 16, 0, 0);
            __builtin_amdgcn_global_load_lds(
                (const __attribute__((address_space(1))) unsigned int*)srcB,
                (__attribute__((address_space(3))) unsigned int*)(Bs + rb * 32), 16, 0, 0);
        }
        __syncthreads();
        bf16x8 aF[4], bF[4];
        #pragma unroll
        for (int m = 0; m < 4; ++m)
            aF[m] = *(const bf16x8*)(As + (wr*64 + m*16 + fr) * 32 + kb);
        #pragma unroll
        for (int n = 0; n < 4; ++n)
            bF[n] = *(const bf16x8*)(Bs + (wc*64 + n*16 + fr) * 32 + kb);
        #pragma unroll
        for (int m = 0; m < 4; ++m)
            #pragma unroll
            for (int n = 0; n < 4; ++n)
                acc[m][n] = __builtin_amdgcn_mfma_f32_16x16x32_bf16(aF[m], bF[n], acc[m][n], 0, 0, 0);
        __syncthreads();
    }
    unsigned short* Ep = E + (size_t)b * NN_ * NN_;
    const int cn = lane & 15;
    const int r0 = (lane >> 4) * 4;
    float cs[4] = {0.f, 0.f, 0.f, 0.f};
    #pragma unroll
    for (int m = 0; m < 4; ++m)
        #pragma unroll
        for (int n = 0; n < 4; ++n)
            #pragma unroll
            for (int r = 0; r < 4; ++r) {
                float e = __expf(acc[m][n][r]);
                Ep[(size_t)(i0 + wr*64 + m*16 + r0 + r) * NN_ + j0 + wc*64 + n*16 + cn] = f2b(e);
                cs[n] += e;
            }
    #pragma unroll
    for (int n = 0; n < 4; ++n) {
        float s = cs[n];
        s += __shfl_xor(s, 16);
        s += __shfl_xor(s, 32);
        if (lane < 16)
            atomicAdd(&colsum[b * NN_ + j0 + wc*64 + n*16 + cn], s);
    }
}

// ---- rhs_c quarter-partials, software-pipelined staging ----
#define XSS 48
__global__ __launch_bounds__(256) void k_rhsc(
    const unsigned short* __restrict__ chebb, const unsigned short* __restrict__ expS,
    const float* __restrict__ colsum, const float* __restrict__ x,
    float* __restrict__ rhsc)
{
    __shared__ float w[3 * 16 * 64];      // 12 KB
    __shared__ float xs[16 * XSS];        // 3 KB
    __shared__ float red[256 * 9];        // 9 KB
    const int m0 = blockIdx.x * 64;
    const int b  = blockIdx.y;
    const int z  = blockIdx.z;
    const int nbase = z * 256;
    const int tid = threadIdx.x;
    const int usplit = tid >> 6;
    const int lane = tid & 63;
    const int mg = lane >> 2;
    const int q  = lane & 3;
    const int nn  = tid >> 4;
    const int mm  = (tid & 15) << 2;
    float rcs[4];
    {
        const float* cp = colsum + b * NN_ + m0 + mm;
        rcs[0] = 1.f / cp[0]; rcs[1] = 1.f / cp[1];
        rcs[2] = 1.f / cp[2]; rcs[3] = 1.f / cp[3];
    }
    // xs staging mapping for idx = tid, tid+256, tid+512 (<576)
    int xlds[3], xsrc[3];
    bool xok[3];
    #pragma unroll
    for (int j = 0; j < 3; ++j) {
        const int idx = tid + j * 256;
        xok[j] = idx < 576;
        const int n2 = idx / 36, jj = idx - n2 * 36;
        const int sec = jj / 9, off = jj - sec * 9;
        xlds[j] = n2 * XSS + sec * 12 + off;
        xsrc[j] = n2 * 36 + jj;
    }

    float acc[3][4][9];
    #pragma unroll
    for (int k = 0; k < 3; ++k)
        #pragma unroll
        for (int mi = 0; mi < 4; ++mi)
            #pragma unroll
            for (int jj = 0; jj < 9; ++jj) acc[k][mi][jj] = 0.f;

    const unsigned short* sb = expS + (size_t)b * NN_ * NN_;
    const float* xb = x + (size_t)b * NN_ * 36;
    const size_t rowoff = (size_t)nn * NN_ + m0 + mm;

    ushort4 ps, pc0, pc1, pc2;
    float px[3];
    // prefetch step 0
    {
        const size_t r = (size_t)nbase * NN_ + rowoff;
        ps  = *(const ushort4*)(sb + r);
        pc0 = *(const ushort4*)(chebb + r);
        pc1 = *(const ushort4*)(chebb + (size_t)NN_ * NN_ + r);
        pc2 = *(const ushort4*)(chebb + (size_t)2 * NN_ * NN_ + r);
        #pragma unroll
        for (int j = 0; j < 3; ++j)
            if (xok[j]) px[j] = xb[(size_t)nbase * 36 + xsrc[j]];
    }

    for (int s = 0; s < 16; ++s) {
        // ---- write prefetched step to LDS ----
        {
            const float st0 = b2f(ps.x) * rcs[0], st1 = b2f(ps.y) * rcs[1];
            const float st2 = b2f(ps.z) * rcs[2], st3 = b2f(ps.w) * rcs[3];
            float4 w0, w1, w2;
            w0.x = b2f(pc0.x)*st0; w0.y = b2f(pc0.y)*st1; w0.z = b2f(pc0.z)*st2; w0.w = b2f(pc0.w)*st3;
            w1.x = b2f(pc1.x)*st0; w1.y = b2f(pc1.y)*st1; w1.z = b2f(pc1.z)*st2; w1.w = b2f(pc1.w)*st3;
            w2.x = b2f(pc2.x)*st0; w2.y = b2f(pc2.y)*st1; w2.z = b2f(pc2.z)*st2; w2.w = b2f(pc2.w)*st3;
            *(float4*)&w[(0 * 16 + nn) * 64 + mm] = w0;
            *(float4*)&w[(1 * 16 + nn) * 64 + mm] = w1;
            *(float4*)&w[(2 * 16 + nn) * 64 + mm] = w2;
            #pragma unroll
            for (int j = 0; j < 3; ++j)
                if (xok[j]) xs[xlds[j]] = px[j];
        }
        __syncthreads();
        // ---- prefetch next step ----
        if (s + 1 < 16) {
            const int n1 = nbase + (s + 1) * 16;
            const size_t r = (size_t)n1 * NN_ + rowoff;
            ps  = *(const ushort4*)(sb + r);
            pc0 = *(const ushort4*)(chebb + r);
            pc1 = *(const ushort4*)(chebb + (size_t)NN_ * NN_ + r);
            pc2 = *(const ushort4*)(chebb + (size_t)2 * NN_ * NN_ + r);
            #pragma unroll
            for (int j = 0; j < 3; ++j)
                if (xok[j]) px[j] = xb[(size_t)n1 * 36 + xsrc[j]];
        }
        // ---- compute current step ----
        #pragma unroll
        for (int ui = 0; ui < 4; ++ui) {
            const int u = usplit * 4 + ui;
            float xv[9];
            *(float4*)&xv[0] = *(const float4*)&xs[u * XSS + q * 12];
            *(float4*)&xv[4] = *(const float4*)&xs[u * XSS + q * 12 + 4];
            xv[8] = xs[u * XSS + q * 12 + 8];
            float wv[3][4];
            #pragma unroll
            for (int k = 0; k < 3; ++k)
                *(float4*)&wv[k][0] = *(const float4*)&w[(k * 16 + u) * 64 + mg * 4];
            #pragma unroll
            for (int k = 0; k < 3; ++k)
                #pragma unroll
                for (int mi = 0; mi < 4; ++mi) {
                    const float wk = wv[k][mi];
                    #pragma unroll
                    for (int jj = 0; jj < 9; ++jj)
                        acc[k][mi][jj] += wk * xv[jj];
                }
        }
        __syncthreads();
    }

    // ---- cross-wave reduction + store ----
    float* outb = rhsc + (size_t)z * RHSC_SZ;
    #pragma unroll
    for (int r = 0; r < 12; ++r) {
        const int k = r >> 2, mi = r & 3;
        #pragma unroll
        for (int jj = 0; jj < 9; ++jj) red[tid * 9 + jj] = acc[k][mi][jj];
        __syncthreads();
        if (usplit == 0) {
            float s[9];
            #pragma unroll
            for (int jj = 0; jj < 9; ++jj)
                s[jj] = red[lane * 9 + jj] + red[(64 + lane) * 9 + jj]
                      + red[(128 + lane) * 9 + jj] + red[(192 + lane) * 9 + jj];
            float* rp = outb + (((size_t)b * 3 + k) * NN_ + m0 + mg * 4 + mi) * 36 + q * 9;
            #pragma unroll
            for (int jj = 0; jj < 9; ++jj) rp[jj] = s[jj];
        }
        __syncthreads();
    }
}

// ---- fused gcn + tconv (3 shifted GEMMs, transposed out[c][nt]) + residual + relu ----
#define G2S 72
#define RSTR 112
__global__ __launch_bounds__(256) void k_y7(
    const float* __restrict__ rhsc,
    const unsigned short* __restrict__ WtG,
    const float* __restrict__ Theta, const float* __restrict__ x,
    const float* __restrict__ tcb,
    const float* __restrict__ rcw, const float* __restrict__ rcb,
    float* __restrict__ y, float* __restrict__ partials)
{
    __shared__ unsigned short Gs2[193 * G2S];
    __shared__ float Rs[16 * RSTR];
    __shared__ float xls[16 * 36];
    __shared__ float red[8];
    const int tid = threadIdx.x;
    const int wid = tid >> 6, lane = tid & 63;
    const int blk = blockIdx.x;

    const int bb = (blk * 16) >> 10;
    const int nb = (blk * 16) & 1023;
    for (int idx = tid; idx < 432; idx += 256) {
        const int i = idx / 27;
        const int r = idx - i * 27;
        const int k = r / 9;
        const int q = r - k * 9;
        const size_t off = (((size_t)bb * 3 + k) * NN_ + nb + i) * 36 + q * 4;
        float4 a = *(const float4*)(rhsc + off);
        float4 b = *(const float4*)(rhsc + RHSC_SZ + off);
        float4 c = *(const float4*)(rhsc + 2 * RHSC_SZ + off);
        float4 d = *(const float4*)(rhsc + 3 * RHSC_SZ + off);
        a.x += b.x + c.x + d.x; a.y += b.y + c.y + d.y;
        a.z += b.z + c.z + d.z; a.w += b.w + c.w + d.w;
        *(float4*)&Rs[i * RSTR + k * 36 + q * 4] = a;
    }
    if (tid < 36) ((unsigned int*)(Gs2 + 192 * G2S))[tid] = 0u;
    if (tid < 144)
        ((float4*)xls)[tid] = ((const float4*)(x + (size_t)blk * 16 * 36))[tid];
    __syncthreads();

    {
        float th[9];
        #pragma unroll
        for (int j = 0; j < 9; ++j) th[j] = Theta[j * 64 + lane];
        #pragma unroll
        for (int ii = 0; ii < 4; ++ii) {
            const int i = wid * 4 + ii;
            float g[12];
            #pragma unroll
            for (int t = 0; t < 12; ++t) g[t] = 0.f;
            #pragma unroll
            for (int kf = 0; kf < 9; ++kf) {
                const float* rp = Rs + i * RSTR + kf * 12;
                float4 v0 = *(const float4*)(rp);
                float4 v1 = *(const float4*)(rp + 4);
                float4 v2 = *(const float4*)(rp + 8);
                const float w = th[kf];
                g[0] += v0.x*w; g[1] += v0.y*w; g[2]  += v0.z*w; g[3]  += v0.w*w;
                g[4] += v1.x*w; g[5] += v1.y*w; g[6]  += v1.z*w; g[7]  += v1.w*w;
                g[8] += v2.x*w; g[9] += v2.y*w; g[10] += v2.z*w; g[11] += v2.w*w;
            }
            #pragma unroll
            for (int t = 0; t < 12; ++t)
                Gs2[(i*12 + t) * G2S + lane] = f2b(fmaxf(g[t], 0.f));
        }
    }
    __syncthreads();

    const int cl = lane & 15, kg = lane >> 4;
    bf16x8 aW[3][2];
    #pragma unroll
    for (int d = 0; d < 3; ++d)
        #pragma unroll
        for (int kb = 0; kb < 2; ++kb)
            aW[d][kb] = *(const bf16x8*)(WtG + (d*64 + wid*16 + cl) * 64 + kb*32 + kg*8);
    float tb[4], rb[4], rw0[4], rw1[4], rw2[4];
    #pragma unroll
    for (int r = 0; r < 4; ++r) {
        const int c = wid*16 + kg*4 + r;
        tb[r] = tcb[c]; rb[r] = rcb[c];
        rw0[r] = rcw[c*3]; rw1[r] = rcw[c*3+1]; rw2[r] = rcw[c*3+2];
    }
    float ls = 0.f, lss = 0.f;
    #pragma unroll
    for (int ct = 0; ct < 12; ++ct) {
        const int nt = ct * 16 + cl;
        const int i = nt / 12;
        const int t = nt - i * 12;
        const unsigned short* g1 = Gs2 + nt * G2S + kg * 8;
        const unsigned short* g0 = (t == 0)  ? (Gs2 + 192 * G2S + kg * 8) : (g1 - G2S);
        const unsigned short* g2 = (t == 11) ? (Gs2 + 192 * G2S + kg * 8) : (g1 + G2S);
        f32x4 a4 = {0.f, 0.f, 0.f, 0.f};
        #pragma unroll
        for (int kb = 0; kb < 2; ++kb) {
            a4 = __builtin_amdgcn_mfma_f32_16x16x32_bf16(aW[0][kb], *(const bf16x8*)(g0 + kb*32), a4, 0, 0, 0);
            a4 = __builtin_amdgcn_mfma_f32_16x16x32_bf16(aW[1][kb], *(const bf16x8*)(g1 + kb*32), a4, 0, 0, 0);
            a4 = __builtin_amdgcn_mfma_f32_16x16x32_bf16(aW[2][kb], *(const bf16x8*)(g2 + kb*32), a4, 0, 0, 0);
        }
        const float x0 = xls[i*36 + t];
        const float x1 = xls[i*36 + 12 + t];
        const float x2 = xls[i*36 + 24 + t];
        float* yp = y + (size_t)(blk*16 + i) * 768 + (wid*16 + kg*4) * 12 + t;
        #pragma unroll
        for (int r = 0; r < 4; ++r) {
            const float xres = rb[r] + x0*rw0[r] + x1*rw1[r] + x2*rw2[r];
            const float v = fmaxf(xres + a4[r] + tb[r], 0.f);
            ls += v; lss += v * v;
            yp[r * 12] = v;
        }
    }
    ls  = wave_reduce_sum(ls);
    lss = wave_reduce_sum(lss);
    if (lane == 0) { red[wid] = ls; red[4 + wid] = lss; }
    __syncthreads();
    if (tid == 0) {
        partials[blk]        = red[0] + red[1] + red[2] + red[3];
        partials[1024 + blk] = red[4] + red[5] + red[6] + red[7];
    }
}

// ---------------- reduce partials -> mean / inv_std ----------------
__global__ __launch_bounds__(256) void k_fin2(
    const float* __restrict__ partials, float* __restrict__ acc)
{
    const int tid = threadIdx.x;
    const int wid = tid >> 6, lane = tid & 63;
    float s = 0.f, ss = 0.f;
    #pragma unroll
    for (int j = tid; j < 1024; j += 256) {
        s  += partials[j];
        ss += partials[1024 + j];
    }
    s  = wave_reduce_sum(s);
    ss = wave_reduce_sum(ss);
    __shared__ float rs[4], rss[4];
    if (lane == 0) { rs[wid] = s; rss[wid] = ss; }
    __syncthreads();
    if (tid == 0) {
        const float cnt = (float)((size_t)BB * NN_ * 64 * TT);
        float tot  = rs[0] + rs[1] + rs[2] + rs[3];
        float tots = rss[0] + rss[1] + rss[2] + rss[3];
        float mu = tot / cnt;
        float var = tots / cnt - mu * mu;
        acc[2] = mu;
        acc[3] = rsqrtf(var + 1e-5f);
    }
}

// ---------------- normalize in place on d_out ----------------
__global__ __launch_bounds__(256) void k_norm(
    float* __restrict__ y, const float* __restrict__ lng,
    const float* __restrict__ lnb, const float* __restrict__ acc)
{
    const unsigned int i = blockIdx.x * 256u + threadIdx.x;
    const float mu = acc[2], inv = acc[3];
    float4 v  = ((const float4*)y)[i];
    float4 gv = ((const float4*)lng)[i];
    float4 bv = ((const float4*)lnb)[i];
    v.x = (v.x - mu) * inv * gv.x + bv.x;
    v.y = (v.y - mu) * inv * gv.y + bv.y;
    v.z = (v.z - mu) * inv * gv.z + bv.z;
    v.w = (v.w - mu) * inv * gv.w + bv.w;
    ((float4*)y)[i] = v;
}

extern "C" void kernel_launch(void* const* d_in, const int* in_sizes, int n_in,
                              void* d_out, int out_size, void* d_ws, size_t ws_size,
                              hipStream_t stream)
{
    const float* x    = (const float*)d_in[0];
    const float* U1   = (const float*)d_in[1];
    const float* U2   = (const float*)d_in[2];
    const float* U3   = (const float*)d_in[3];
    const float* be   = (const float*)d_in[4];
    const float* Ve   = (const float*)d_in[5];
    const float* W1   = (const float*)d_in[6];
    const float* W2   = (const float*)d_in[7];
    const float* W3   = (const float*)d_in[8];
    const float* bs   = (const float*)d_in[9];
    const float* Vs   = (const float*)d_in[10];
    const float* cheb = (const float*)d_in[11];
    const float* Th   = (const float*)d_in[12];
    const float* tcw  = (const float*)d_in[13];
    const float* tcb  = (const float*)d_in[14];
    const float* rcw  = (const float*)d_in[15];
    const float* rcb  = (const float*)d_in[16];
    const float* lng  = (const float*)d_in[17];
    const float* lnb  = (const float*)d_in[18];
    float* out = (float*)d_out;
    float* ws  = (float*)d_ws;

    float* acc    = ws + ACC_OFF;
    float* colsum = ws + COLSUM_OFF;
    float* tat    = ws + TAT_OFF;
    float* lhsT   = ws + LHST_OFF;
    float* rhs2   = ws + RHS2_OFF;
    unsigned short* Vsb   = (unsigned short*)(ws + VSB_OFF);
    unsigned short* sig2b = (unsigned short*)(ws + SIG2B_OFF);
    unsigned short* chebb = (unsigned short*)(ws + CHEBB_OFF);
    unsigned short* expS  = (unsigned short*)(ws + EXPS_OFF);
    float* rhsc   = ws + RHSC_OFF;
    unsigned short* WtG   = (unsigned short*)(ws + WTG_OFF);
    float* partials = ws + PART_OFF;

    k_init<<<65, 256, 0, stream>>>(ws);
    k_cvtw<<<1, 256, 0, stream>>>(tcw, WtG);
    k_temporal<<<BB, 256, 0, stream>>>(x, U1, U2, U3, be, Ve, tat);
    k_xtat<<<(BB * NN_) / 256, 256, 0, stream>>>(x, tat, W1, W2, W3, lhsT, rhs2);
    k_cvt4<<<(NN_ * NN_) / 1024, 256, 0, stream>>>(Vs, Vsb);
    k_cvt4<<<(3 * NN_ * NN_) / 1024, 256, 0, stream>>>(cheb, chebb);
    k_sig2<<<(BB * NN_ * NN_) / 256, 256, 0, stream>>>(lhsT, rhs2, bs, (__hip_bfloat16*)sig2b);
    k_gemm_s_mfma<<<dim3(8, 8, BB), 256, 0, stream>>>((const short*)sig2b, (const short*)Vsb, expS, colsum);
    k_rhsc<<<dim3(16, BB, 4), 256, 0, stream>>>(chebb, expS, colsum, x, rhsc);
    k_y7<<<(BB * NN_) / 16, 256, 0, stream>>>(rhsc, WtG, Th, x, tcb, rcw, rcb, out, partials);
    k_fin2<<<1, 256, 0, stream>>>(partials, acc);
    k_norm<<<(BB * NN_ * 64 * TT) / 4 / 256, 256, 0, stream>>>(out, lng, lnb, acc);
}